// Round 1
// baseline (1326.278 us; speedup 1.0000x reference)
//
#include <hip/hip_runtime.h>

// LightGCN on MI355X.
// Pipeline per call (graph-capturable, stream-only):
//  1. memset deg/cursor
//  2. init_concat: x0 = acc = [user_emb; item_emb]         (float4 vectorized)
//  3. count_deg  : deg[r]++ per edge (int atomics)
//  4. 2-level exclusive scan -> row_ptr (CSR offsets)
//  5. fill_csr   : scatter (cols, vals) into CSR slots
//  6. 3x spmm    : one wave per row; lane=dim; acc += out  (no output atomics)
//  7. score      : one wave per batch elem, shuffle-reduce dot, /16

#define DIM 64

__global__ __launch_bounds__(256) void init_concat(
    const float4* __restrict__ ue, const float4* __restrict__ ie,
    int nu4, int total4, float4* __restrict__ x, float4* __restrict__ acc) {
  int i = blockIdx.x * 256 + threadIdx.x;
  if (i < total4) {
    float4 v = (i < nu4) ? ue[i] : ie[i - nu4];
    x[i] = v;
    acc[i] = v;
  }
}

__global__ __launch_bounds__(256) void count_deg(
    const int* __restrict__ rows, int nnz, int* __restrict__ deg) {
  int e = blockIdx.x * 256 + threadIdx.x;
  if (e < nnz) atomicAdd(&deg[rows[e]], 1);
}

// inclusive scan of 256-element chunks; per-chunk totals to partials
__global__ __launch_bounds__(256) void scan_chunks(
    const int* __restrict__ deg, int n, int* __restrict__ scanned,
    int* __restrict__ partials) {
  __shared__ int s[256];
  int t = threadIdx.x;
  int g = blockIdx.x * 256 + t;
  s[t] = (g < n) ? deg[g] : 0;
  __syncthreads();
  for (int off = 1; off < 256; off <<= 1) {
    int v = (t >= off) ? s[t - off] : 0;
    __syncthreads();
    s[t] += v;
    __syncthreads();
  }
  if (g < n) scanned[g] = s[t];
  if (t == 255) partials[blockIdx.x] = s[255];
}

// single-block exclusive scan of the (<=1024) chunk totals, in place
__global__ __launch_bounds__(1024) void scan_partials(
    int* __restrict__ partials, int nblk) {
  __shared__ int s[1024];
  int t = threadIdx.x;
  s[t] = (t < nblk) ? partials[t] : 0;
  __syncthreads();
  for (int off = 1; off < 1024; off <<= 1) {
    int v = (t >= off) ? s[t - off] : 0;
    __syncthreads();
    s[t] += v;
    __syncthreads();
  }
  if (t < nblk) partials[t] = (t == 0) ? 0 : s[t - 1];
}

__global__ __launch_bounds__(256) void finalize_rowptr(
    const int* __restrict__ scanned, const int* __restrict__ partials, int n,
    int* __restrict__ row_ptr) {
  int g = blockIdx.x * 256 + threadIdx.x;
  if (g < n) row_ptr[g + 1] = scanned[g] + partials[blockIdx.x];
  if (g == 0) row_ptr[0] = 0;
}

__global__ __launch_bounds__(256) void fill_csr(
    const int* __restrict__ rows, const int* __restrict__ cols,
    const float* __restrict__ vals, int nnz, const int* __restrict__ row_ptr,
    int* __restrict__ cursor, int* __restrict__ csr_cols,
    float* __restrict__ csr_vals) {
  int e = blockIdx.x * 256 + threadIdx.x;
  if (e < nnz) {
    int r = rows[e];
    int p = row_ptr[r] + atomicAdd(&cursor[r], 1);
    csr_cols[p] = cols[e];
    csr_vals[p] = vals[e];
  }
}

// one wave (64 lanes) per row; lane = embedding dim
__global__ __launch_bounds__(256) void spmm(
    const int* __restrict__ row_ptr, const int* __restrict__ csr_cols,
    const float* __restrict__ csr_vals, const float* __restrict__ x_in,
    float* __restrict__ x_out, float* __restrict__ acc, int n) {
  int w = (blockIdx.x * 256 + threadIdx.x) >> 6;
  int lane = threadIdx.x & 63;
  if (w >= n) return;
  int start = row_ptr[w];
  int end = row_ptr[w + 1];
  float sum = 0.f;
  for (int k = start; k < end; ++k) {
    int c = csr_cols[k];      // wave-uniform
    float v = csr_vals[k];    // wave-uniform
    sum += v * x_in[c * DIM + lane];
  }
  int o = w * DIM + lane;
  x_out[o] = sum;
  acc[o] += sum;
}

__global__ __launch_bounds__(256) void score(
    const float* __restrict__ acc, const int* __restrict__ user_ids,
    const int* __restrict__ item_ids, int num_user, int batch,
    float* __restrict__ out) {
  int w = (blockIdx.x * 256 + threadIdx.x) >> 6;
  int lane = threadIdx.x & 63;
  if (w >= batch) return;
  int u = user_ids[w];
  int it = item_ids[w] + num_user;
  float p = acc[u * DIM + lane] * acc[it * DIM + lane];
  for (int off = 32; off > 0; off >>= 1) p += __shfl_down(p, off, 64);
  if (lane == 0) out[w] = p * (1.0f / 16.0f);  // (acc/4)·(acc/4)
}

extern "C" void kernel_launch(void* const* d_in, const int* in_sizes, int n_in,
                              void* d_out, int out_size, void* d_ws, size_t ws_size,
                              hipStream_t stream) {
  const float* user_emb = (const float*)d_in[0];
  const float* item_emb = (const float*)d_in[1];
  const float* adj_vals = (const float*)d_in[2];
  const int* adj_rows = (const int*)d_in[3];
  const int* adj_cols = (const int*)d_in[4];
  const int* user_ids = (const int*)d_in[5];
  const int* item_ids = (const int*)d_in[6];
  float* scores = (float*)d_out;

  const int U = in_sizes[0] / DIM;       // 100000
  const int I = in_sizes[1] / DIM;       // 50000
  const int N = U + I;                   // 150000
  const int nnz = in_sizes[2];           // 3200000
  const int B = in_sizes[5];             // 4096

  // carve workspace (256B aligned partitions)
  char* p = (char*)d_ws;
  auto carve = [&](size_t bytes) {
    void* r = (void*)p;
    p += (bytes + 255) & ~(size_t)255;
    return r;
  };
  float* x_a = (float*)carve((size_t)N * DIM * 4);
  float* x_b = (float*)carve((size_t)N * DIM * 4);
  float* acc = (float*)carve((size_t)N * DIM * 4);
  int* deg = (int*)carve((size_t)N * 4);
  int* row_ptr = (int*)carve((size_t)(N + 1) * 4);
  int* cursor = (int*)carve((size_t)N * 4);
  int* scanned = (int*)carve((size_t)N * 4);
  int* partials = (int*)carve((size_t)1024 * 4);
  int* csr_cols = (int*)carve((size_t)nnz * 4);
  float* csr_vals = (float*)carve((size_t)nnz * 4);

  hipMemsetAsync(deg, 0, (size_t)N * 4, stream);
  hipMemsetAsync(cursor, 0, (size_t)N * 4, stream);

  const int total4 = N * (DIM / 4);
  const int nu4 = U * (DIM / 4);
  init_concat<<<(total4 + 255) / 256, 256, 0, stream>>>(
      (const float4*)user_emb, (const float4*)item_emb, nu4, total4,
      (float4*)x_a, (float4*)acc);

  const int eblocks = (nnz + 255) / 256;
  count_deg<<<eblocks, 256, 0, stream>>>(adj_rows, nnz, deg);

  const int nblk = (N + 255) / 256;  // 586 <= 1024
  scan_chunks<<<nblk, 256, 0, stream>>>(deg, N, scanned, partials);
  scan_partials<<<1, 1024, 0, stream>>>(partials, nblk);
  finalize_rowptr<<<nblk, 256, 0, stream>>>(scanned, partials, N, row_ptr);

  fill_csr<<<eblocks, 256, 0, stream>>>(adj_rows, adj_cols, adj_vals, nnz,
                                        row_ptr, cursor, csr_cols, csr_vals);

  const int rblocks = (N + 3) / 4;  // 4 waves (rows) per 256-thread block
  float* xin = x_a;
  float* xout = x_b;
  for (int l = 0; l < 3; ++l) {
    spmm<<<rblocks, 256, 0, stream>>>(row_ptr, csr_cols, csr_vals, xin, xout,
                                      acc, N);
    float* t = xin; xin = xout; xout = t;
  }

  score<<<(B + 3) / 4, 256, 0, stream>>>(acc, user_ids, item_ids, U, B, scores);
}

// Round 2
// 750.087 us; speedup vs baseline: 1.7682x; 1.7682x over previous
//
#include <hip/hip_runtime.h>

// LightGCN on MI355X — round 1.
// SpMM: wave=64 split into 4 sub-groups x 16 lanes; 4 edges in flight per
// load instruction (float4 per lane), unroll x2 => 8 edges/iter, ~2.7 iters
// per row at avg degree 21. CSR packed as int2{col, bits(val)}.
// acc eliminated: score sums x0(from inputs)+x1+x2+x3 at its 8192 rows.

#define DIM 64

__global__ __launch_bounds__(256) void init_concat(
    const float4* __restrict__ ue, const float4* __restrict__ ie,
    int nu4, int total4, float4* __restrict__ x) {
  int i = blockIdx.x * 256 + threadIdx.x;
  if (i < total4) x[i] = (i < nu4) ? ue[i] : ie[i - nu4];
}

__global__ __launch_bounds__(256) void count_deg(
    const int4* __restrict__ rows4, int nnz4, int* __restrict__ deg) {
  int i = blockIdx.x * 256 + threadIdx.x;
  if (i < nnz4) {
    int4 r = rows4[i];
    atomicAdd(&deg[r.x], 1);
    atomicAdd(&deg[r.y], 1);
    atomicAdd(&deg[r.z], 1);
    atomicAdd(&deg[r.w], 1);
  }
}

__global__ __launch_bounds__(256) void count_deg_tail(
    const int* __restrict__ rows, int start, int nnz, int* __restrict__ deg) {
  int e = start + blockIdx.x * 256 + threadIdx.x;
  if (e < nnz) atomicAdd(&deg[rows[e]], 1);
}

// inclusive scan of 256-element chunks; per-chunk totals to partials
__global__ __launch_bounds__(256) void scan_chunks(
    const int* __restrict__ deg, int n, int* __restrict__ scanned,
    int* __restrict__ partials) {
  __shared__ int s[256];
  int t = threadIdx.x;
  int g = blockIdx.x * 256 + t;
  s[t] = (g < n) ? deg[g] : 0;
  __syncthreads();
  for (int off = 1; off < 256; off <<= 1) {
    int v = (t >= off) ? s[t - off] : 0;
    __syncthreads();
    s[t] += v;
    __syncthreads();
  }
  if (g < n) scanned[g] = s[t];
  if (t == 255) partials[blockIdx.x] = s[255];
}

__global__ __launch_bounds__(1024) void scan_partials(
    int* __restrict__ partials, int nblk) {
  __shared__ int s[1024];
  int t = threadIdx.x;
  s[t] = (t < nblk) ? partials[t] : 0;
  __syncthreads();
  for (int off = 1; off < 1024; off <<= 1) {
    int v = (t >= off) ? s[t - off] : 0;
    __syncthreads();
    s[t] += v;
    __syncthreads();
  }
  if (t < nblk) partials[t] = (t == 0) ? 0 : s[t - 1];
}

// row_ptr[r+1] = inclusive[r]; cursor[r] = start-of-row (= incl - deg)
__global__ __launch_bounds__(256) void finalize_rowptr(
    const int* __restrict__ scanned, const int* __restrict__ partials,
    const int* __restrict__ deg, int n, int* __restrict__ row_ptr,
    int* __restrict__ cursor) {
  int g = blockIdx.x * 256 + threadIdx.x;
  if (g < n) {
    int incl = scanned[g] + partials[blockIdx.x];
    row_ptr[g + 1] = incl;
    cursor[g] = incl - deg[g];
  }
  if (g == 0) row_ptr[0] = 0;
}

__global__ __launch_bounds__(256) void fill_csr(
    const int* __restrict__ rows, const int* __restrict__ cols,
    const float* __restrict__ vals, int nnz, int* __restrict__ cursor,
    int2* __restrict__ csr) {
  int e = blockIdx.x * 256 + threadIdx.x;
  if (e < nnz) {
    int r = rows[e];
    int p = atomicAdd(&cursor[r], 1);
    int2 cv;
    cv.x = cols[e];
    cv.y = __float_as_int(vals[e]);
    csr[p] = cv;
  }
}

// one wave per row; 4 sub-groups x 16 lanes; float4 per lane; unroll x2
__global__ __launch_bounds__(256) void spmm4(
    const int* __restrict__ row_ptr, const int2* __restrict__ csr,
    const float* __restrict__ x_in, float* __restrict__ x_out, int n) {
  int w = (blockIdx.x * 256 + threadIdx.x) >> 6;
  int lane = threadIdx.x & 63;
  if (w >= n) return;
  int s = lane >> 4;        // edge slot 0..3
  int d4 = (lane & 15) * 4; // dim offset
  int start = row_ptr[w];
  int end = row_ptr[w + 1];
  float4 sum = {0.f, 0.f, 0.f, 0.f};
  for (int k = start + s; k < end; k += 8) {
    int k2 = k + 4;
    bool ok2 = k2 < end;
    int2 cv0 = csr[k];
    int2 cv1 = csr[ok2 ? k2 : k];
    const float4 g0 = *(const float4*)(x_in + (size_t)cv0.x * DIM + d4);
    const float4 g1 = *(const float4*)(x_in + (size_t)cv1.x * DIM + d4);
    float v0 = __int_as_float(cv0.y);
    float v1 = ok2 ? __int_as_float(cv1.y) : 0.f;
    sum.x += v0 * g0.x; sum.y += v0 * g0.y;
    sum.z += v0 * g0.z; sum.w += v0 * g0.w;
    sum.x += v1 * g1.x; sum.y += v1 * g1.y;
    sum.z += v1 * g1.z; sum.w += v1 * g1.w;
  }
  // reduce across the 4 edge-slots (lanes differing in bits 4..5)
  sum.x += __shfl_xor(sum.x, 16, 64); sum.y += __shfl_xor(sum.y, 16, 64);
  sum.z += __shfl_xor(sum.z, 16, 64); sum.w += __shfl_xor(sum.w, 16, 64);
  sum.x += __shfl_xor(sum.x, 32, 64); sum.y += __shfl_xor(sum.y, 32, 64);
  sum.z += __shfl_xor(sum.z, 32, 64); sum.w += __shfl_xor(sum.w, 32, 64);
  if (lane < 16) *(float4*)(x_out + (size_t)w * DIM + d4) = sum;
}

__global__ __launch_bounds__(256) void score(
    const float* __restrict__ ue, const float* __restrict__ ie,
    const float* __restrict__ x1, const float* __restrict__ x2,
    const float* __restrict__ x3, const int* __restrict__ user_ids,
    const int* __restrict__ item_ids, int num_user, int batch,
    float* __restrict__ out) {
  int w = (blockIdx.x * 256 + threadIdx.x) >> 6;
  int lane = threadIdx.x & 63;
  if (w >= batch) return;
  int u = user_ids[w];
  int iti = item_ids[w];
  int it = iti + num_user;
  size_t uo = (size_t)u * DIM + lane;
  size_t io = (size_t)it * DIM + lane;
  float a = ue[uo] + x1[uo] + x2[uo] + x3[uo];
  float b = ie[(size_t)iti * DIM + lane] + x1[io] + x2[io] + x3[io];
  float p = a * b;
  for (int off = 32; off > 0; off >>= 1) p += __shfl_down(p, off, 64);
  if (lane == 0) out[w] = p * (1.0f / 16.0f);  // (sum/4)·(sum/4)
}

extern "C" void kernel_launch(void* const* d_in, const int* in_sizes, int n_in,
                              void* d_out, int out_size, void* d_ws, size_t ws_size,
                              hipStream_t stream) {
  const float* user_emb = (const float*)d_in[0];
  const float* item_emb = (const float*)d_in[1];
  const float* adj_vals = (const float*)d_in[2];
  const int* adj_rows = (const int*)d_in[3];
  const int* adj_cols = (const int*)d_in[4];
  const int* user_ids = (const int*)d_in[5];
  const int* item_ids = (const int*)d_in[6];
  float* scores = (float*)d_out;

  const int U = in_sizes[0] / DIM;  // 100000
  const int I = in_sizes[1] / DIM;  // 50000
  const int N = U + I;              // 150000
  const int nnz = in_sizes[2];      // 3200000
  const int B = in_sizes[5];        // 4096

  char* p = (char*)d_ws;
  auto carve = [&](size_t bytes) {
    void* r = (void*)p;
    p += (bytes + 255) & ~(size_t)255;
    return r;
  };
  float* x0 = (float*)carve((size_t)N * DIM * 4);  // layer-0 concat; reused as x3
  float* x1 = (float*)carve((size_t)N * DIM * 4);
  float* x2 = (float*)carve((size_t)N * DIM * 4);
  int* deg = (int*)carve((size_t)N * 4);
  int* row_ptr = (int*)carve((size_t)(N + 1) * 4);
  int* cursor = (int*)carve((size_t)N * 4);
  int* scanned = (int*)carve((size_t)N * 4);
  int* partials = (int*)carve((size_t)1024 * 4);
  int2* csr = (int2*)carve((size_t)nnz * 8);
  float* x3 = x0;

  hipMemsetAsync(deg, 0, (size_t)N * 4, stream);

  const int total4 = N * (DIM / 4);
  const int nu4 = U * (DIM / 4);
  init_concat<<<(total4 + 255) / 256, 256, 0, stream>>>(
      (const float4*)user_emb, (const float4*)item_emb, nu4, total4,
      (float4*)x0);

  const int nnz4 = nnz / 4;
  count_deg<<<(nnz4 + 255) / 256, 256, 0, stream>>>((const int4*)adj_rows,
                                                    nnz4, deg);
  if (nnz & 3) {
    count_deg_tail<<<1, 256, 0, stream>>>(adj_rows, nnz4 * 4, nnz, deg);
  }

  const int nblk = (N + 255) / 256;  // 586 <= 1024
  scan_chunks<<<nblk, 256, 0, stream>>>(deg, N, scanned, partials);
  scan_partials<<<1, 1024, 0, stream>>>(partials, nblk);
  finalize_rowptr<<<nblk, 256, 0, stream>>>(scanned, partials, deg, N, row_ptr,
                                            cursor);

  const int eblocks = (nnz + 255) / 256;
  fill_csr<<<eblocks, 256, 0, stream>>>(adj_rows, adj_cols, adj_vals, nnz,
                                        cursor, csr);

  const int rblocks = (N + 3) / 4;  // 4 waves (rows) per block
  spmm4<<<rblocks, 256, 0, stream>>>(row_ptr, csr, x0, x1, N);
  spmm4<<<rblocks, 256, 0, stream>>>(row_ptr, csr, x1, x2, N);
  spmm4<<<rblocks, 256, 0, stream>>>(row_ptr, csr, x2, x3, N);

  score<<<(B + 3) / 4, 256, 0, stream>>>(user_emb, item_emb, x1, x2, x3,
                                         user_ids, item_ids, U, B, scores);
}

// Round 3
// 606.558 us; speedup vs baseline: 2.1866x; 1.2366x over previous
//
#include <hip/hip_runtime.h>

// LightGCN on MI355X — round 2.
//  * fill_csr: row-tiled (8 tiles) with tile = blockIdx%8 XCD-affinity so each
//    tile's 3.2 MB CSR scatter region stays in one XCD's L2 -> full-line
//    writebacks instead of 64B-line-per-8B-store amplification.
//  * layer-1 SpMM reads ue/ie directly (x0 buffer + init kernel eliminated).
//  * layer-3 SpMM fused into score: gather x3 only at the 8192 batch rows.

#define DIM 64
#define NTILE 8

__global__ __launch_bounds__(256) void count_deg(
    const int4* __restrict__ rows4, int nnz4, int* __restrict__ deg) {
  int i = blockIdx.x * 256 + threadIdx.x;
  if (i < nnz4) {
    int4 r = rows4[i];
    atomicAdd(&deg[r.x], 1);
    atomicAdd(&deg[r.y], 1);
    atomicAdd(&deg[r.z], 1);
    atomicAdd(&deg[r.w], 1);
  }
}

__global__ __launch_bounds__(256) void count_deg_tail(
    const int* __restrict__ rows, int start, int nnz, int* __restrict__ deg) {
  int e = start + blockIdx.x * 256 + threadIdx.x;
  if (e < nnz) atomicAdd(&deg[rows[e]], 1);
}

__global__ __launch_bounds__(256) void scan_chunks(
    const int* __restrict__ deg, int n, int* __restrict__ scanned,
    int* __restrict__ partials) {
  __shared__ int s[256];
  int t = threadIdx.x;
  int g = blockIdx.x * 256 + t;
  s[t] = (g < n) ? deg[g] : 0;
  __syncthreads();
  for (int off = 1; off < 256; off <<= 1) {
    int v = (t >= off) ? s[t - off] : 0;
    __syncthreads();
    s[t] += v;
    __syncthreads();
  }
  if (g < n) scanned[g] = s[t];
  if (t == 255) partials[blockIdx.x] = s[255];
}

__global__ __launch_bounds__(1024) void scan_partials(
    int* __restrict__ partials, int nblk) {
  __shared__ int s[1024];
  int t = threadIdx.x;
  s[t] = (t < nblk) ? partials[t] : 0;
  __syncthreads();
  for (int off = 1; off < 1024; off <<= 1) {
    int v = (t >= off) ? s[t - off] : 0;
    __syncthreads();
    s[t] += v;
    __syncthreads();
  }
  if (t < nblk) partials[t] = (t == 0) ? 0 : s[t - 1];
}

__global__ __launch_bounds__(256) void finalize_rowptr(
    const int* __restrict__ scanned, const int* __restrict__ partials,
    const int* __restrict__ deg, int n, int* __restrict__ row_ptr,
    int* __restrict__ cursor) {
  int g = blockIdx.x * 256 + threadIdx.x;
  if (g < n) {
    int incl = scanned[g] + partials[blockIdx.x];
    row_ptr[g + 1] = incl;
    cursor[g] = incl - deg[g];
  }
  if (g == 0) row_ptr[0] = 0;
}

// tiled fill: tile = blockIdx % NTILE (XCD round-robin heuristic); each tile
// owns a contiguous row range so its scatter region (~3.2 MB) is L2-local.
__global__ __launch_bounds__(256) void fill_csr_tiled(
    const int* __restrict__ rows, const int* __restrict__ cols,
    const float* __restrict__ vals, int nnz, int rows_per_tile,
    int stride, int* __restrict__ cursor, int2* __restrict__ csr) {
  int tile = blockIdx.x % NTILE;
  int chunk = blockIdx.x / NTILE;
  int lo = tile * rows_per_tile;
  int hi = lo + rows_per_tile;
  for (int e = chunk * 256 + threadIdx.x; e < nnz; e += stride) {
    int r = rows[e];
    if (r >= lo && r < hi) {
      int p = atomicAdd(&cursor[r], 1);
      int2 cv;
      cv.x = cols[e];
      cv.y = __float_as_int(vals[e]);
      csr[p] = cv;
    }
  }
}

// one wave per row; 4 sub-groups x 16 lanes; float4 per lane; unroll x2.
// Layer 1: gathers straight from ue/ie (x0 never materialized).
__global__ __launch_bounds__(256) void spmm_l1(
    const int* __restrict__ row_ptr, const int2* __restrict__ csr,
    const float* __restrict__ ue, const float* __restrict__ ie, int U,
    float* __restrict__ x_out, int n) {
  int w = (blockIdx.x * 256 + threadIdx.x) >> 6;
  int lane = threadIdx.x & 63;
  if (w >= n) return;
  int s = lane >> 4;
  int d4 = (lane & 15) * 4;
  int start = row_ptr[w];
  int end = row_ptr[w + 1];
  float4 sum = {0.f, 0.f, 0.f, 0.f};
  for (int k = start + s; k < end; k += 8) {
    int k2 = k + 4;
    bool ok2 = k2 < end;
    int2 cv0 = csr[k];
    int2 cv1 = csr[ok2 ? k2 : k];
    int c0 = cv0.x, c1 = cv1.x;
    const float* p0 = (c0 < U) ? (ue + (size_t)c0 * DIM)
                               : (ie + (size_t)(c0 - U) * DIM);
    const float* p1 = (c1 < U) ? (ue + (size_t)c1 * DIM)
                               : (ie + (size_t)(c1 - U) * DIM);
    float4 g0 = *(const float4*)(p0 + d4);
    float4 g1 = *(const float4*)(p1 + d4);
    float v0 = __int_as_float(cv0.y);
    float v1 = ok2 ? __int_as_float(cv1.y) : 0.f;
    sum.x += v0 * g0.x; sum.y += v0 * g0.y;
    sum.z += v0 * g0.z; sum.w += v0 * g0.w;
    sum.x += v1 * g1.x; sum.y += v1 * g1.y;
    sum.z += v1 * g1.z; sum.w += v1 * g1.w;
  }
  sum.x += __shfl_xor(sum.x, 16, 64); sum.y += __shfl_xor(sum.y, 16, 64);
  sum.z += __shfl_xor(sum.z, 16, 64); sum.w += __shfl_xor(sum.w, 16, 64);
  sum.x += __shfl_xor(sum.x, 32, 64); sum.y += __shfl_xor(sum.y, 32, 64);
  sum.z += __shfl_xor(sum.z, 32, 64); sum.w += __shfl_xor(sum.w, 32, 64);
  if (lane < 16) *(float4*)(x_out + (size_t)w * DIM + d4) = sum;
}

__global__ __launch_bounds__(256) void spmm4(
    const int* __restrict__ row_ptr, const int2* __restrict__ csr,
    const float* __restrict__ x_in, float* __restrict__ x_out, int n) {
  int w = (blockIdx.x * 256 + threadIdx.x) >> 6;
  int lane = threadIdx.x & 63;
  if (w >= n) return;
  int s = lane >> 4;
  int d4 = (lane & 15) * 4;
  int start = row_ptr[w];
  int end = row_ptr[w + 1];
  float4 sum = {0.f, 0.f, 0.f, 0.f};
  for (int k = start + s; k < end; k += 8) {
    int k2 = k + 4;
    bool ok2 = k2 < end;
    int2 cv0 = csr[k];
    int2 cv1 = csr[ok2 ? k2 : k];
    float4 g0 = *(const float4*)(x_in + (size_t)cv0.x * DIM + d4);
    float4 g1 = *(const float4*)(x_in + (size_t)cv1.x * DIM + d4);
    float v0 = __int_as_float(cv0.y);
    float v1 = ok2 ? __int_as_float(cv1.y) : 0.f;
    sum.x += v0 * g0.x; sum.y += v0 * g0.y;
    sum.z += v0 * g0.z; sum.w += v0 * g0.w;
    sum.x += v1 * g1.x; sum.y += v1 * g1.y;
    sum.z += v1 * g1.z; sum.w += v1 * g1.w;
  }
  sum.x += __shfl_xor(sum.x, 16, 64); sum.y += __shfl_xor(sum.y, 16, 64);
  sum.z += __shfl_xor(sum.z, 16, 64); sum.w += __shfl_xor(sum.w, 16, 64);
  sum.x += __shfl_xor(sum.x, 32, 64); sum.y += __shfl_xor(sum.y, 32, 64);
  sum.z += __shfl_xor(sum.z, 32, 64); sum.w += __shfl_xor(sum.w, 32, 64);
  if (lane < 16) *(float4*)(x_out + (size_t)w * DIM + d4) = sum;
}

__device__ __forceinline__ float4 gather_row(
    const int* __restrict__ row_ptr, const int2* __restrict__ csr,
    const float* __restrict__ x, int row, int s, int d4) {
  int start = row_ptr[row];
  int end = row_ptr[row + 1];
  float4 sum = {0.f, 0.f, 0.f, 0.f};
  for (int k = start + s; k < end; k += 8) {
    int k2 = k + 4;
    bool ok2 = k2 < end;
    int2 cv0 = csr[k];
    int2 cv1 = csr[ok2 ? k2 : k];
    float4 g0 = *(const float4*)(x + (size_t)cv0.x * DIM + d4);
    float4 g1 = *(const float4*)(x + (size_t)cv1.x * DIM + d4);
    float v0 = __int_as_float(cv0.y);
    float v1 = ok2 ? __int_as_float(cv1.y) : 0.f;
    sum.x += v0 * g0.x; sum.y += v0 * g0.y;
    sum.z += v0 * g0.z; sum.w += v0 * g0.w;
    sum.x += v1 * g1.x; sum.y += v1 * g1.y;
    sum.z += v1 * g1.z; sum.w += v1 * g1.w;
  }
  sum.x += __shfl_xor(sum.x, 16, 64); sum.y += __shfl_xor(sum.y, 16, 64);
  sum.z += __shfl_xor(sum.z, 16, 64); sum.w += __shfl_xor(sum.w, 16, 64);
  sum.x += __shfl_xor(sum.x, 32, 64); sum.y += __shfl_xor(sum.y, 32, 64);
  sum.z += __shfl_xor(sum.z, 32, 64); sum.w += __shfl_xor(sum.w, 32, 64);
  return sum;  // valid in all lanes
}

// fused layer-3 SpMM (batch rows only) + x0..x3 sum + dot-product scorer.
// one wave per batch element.
__global__ __launch_bounds__(256) void spmm3_score(
    const int* __restrict__ row_ptr, const int2* __restrict__ csr,
    const float* __restrict__ ue, const float* __restrict__ ie,
    const float* __restrict__ x1, const float* __restrict__ x2,
    const int* __restrict__ user_ids, const int* __restrict__ item_ids,
    int U, int batch, float* __restrict__ out) {
  int w = (blockIdx.x * 256 + threadIdx.x) >> 6;
  int lane = threadIdx.x & 63;
  if (w >= batch) return;
  int s = lane >> 4;
  int d4 = (lane & 15) * 4;
  int q = lane & 15;
  int u = user_ids[w];
  int iti = item_ids[w];
  int it = iti + U;
  float4 x3u = gather_row(row_ptr, csr, x2, u, s, d4);
  float4 x3i = gather_row(row_ptr, csr, x2, it, s, d4);
  float4 a0 = ((const float4*)ue)[(size_t)u * 16 + q];
  float4 b0 = ((const float4*)ie)[(size_t)iti * 16 + q];
  float4 a1 = ((const float4*)x1)[(size_t)u * 16 + q];
  float4 b1 = ((const float4*)x1)[(size_t)it * 16 + q];
  float4 a2 = ((const float4*)x2)[(size_t)u * 16 + q];
  float4 b2 = ((const float4*)x2)[(size_t)it * 16 + q];
  float ax = a0.x + a1.x + a2.x + x3u.x;
  float ay = a0.y + a1.y + a2.y + x3u.y;
  float az = a0.z + a1.z + a2.z + x3u.z;
  float aw = a0.w + a1.w + a2.w + x3u.w;
  float bx = b0.x + b1.x + b2.x + x3i.x;
  float by = b0.y + b1.y + b2.y + x3i.y;
  float bz = b0.z + b1.z + b2.z + x3i.z;
  float bw = b0.w + b1.w + b2.w + x3i.w;
  float p = ax * bx + ay * by + az * bz + aw * bw;
  p += __shfl_xor(p, 1, 64);
  p += __shfl_xor(p, 2, 64);
  p += __shfl_xor(p, 4, 64);
  p += __shfl_xor(p, 8, 64);
  if (lane == 0) out[w] = p * (1.0f / 16.0f);  // (sum/4)·(sum/4)
}

extern "C" void kernel_launch(void* const* d_in, const int* in_sizes, int n_in,
                              void* d_out, int out_size, void* d_ws, size_t ws_size,
                              hipStream_t stream) {
  const float* user_emb = (const float*)d_in[0];
  const float* item_emb = (const float*)d_in[1];
  const float* adj_vals = (const float*)d_in[2];
  const int* adj_rows = (const int*)d_in[3];
  const int* adj_cols = (const int*)d_in[4];
  const int* user_ids = (const int*)d_in[5];
  const int* item_ids = (const int*)d_in[6];
  float* scores = (float*)d_out;

  const int U = in_sizes[0] / DIM;  // 100000
  const int I = in_sizes[1] / DIM;  // 50000
  const int N = U + I;              // 150000
  const int nnz = in_sizes[2];      // 3200000
  const int B = in_sizes[5];        // 4096

  char* p = (char*)d_ws;
  auto carve = [&](size_t bytes) {
    void* r = (void*)p;
    p += (bytes + 255) & ~(size_t)255;
    return r;
  };
  float* x1 = (float*)carve((size_t)N * DIM * 4);
  float* x2 = (float*)carve((size_t)N * DIM * 4);
  int* deg = (int*)carve((size_t)N * 4);
  int* row_ptr = (int*)carve((size_t)(N + 1) * 4);
  int* cursor = (int*)carve((size_t)N * 4);
  int* scanned = (int*)carve((size_t)N * 4);
  int* partials = (int*)carve((size_t)1024 * 4);
  int2* csr = (int2*)carve((size_t)nnz * 8);

  hipMemsetAsync(deg, 0, (size_t)N * 4, stream);

  const int nnz4 = nnz / 4;
  count_deg<<<(nnz4 + 255) / 256, 256, 0, stream>>>((const int4*)adj_rows,
                                                    nnz4, deg);
  if (nnz & 3) {
    count_deg_tail<<<1, 256, 0, stream>>>(adj_rows, nnz4 * 4, nnz, deg);
  }

  const int nblk = (N + 255) / 256;  // 586 <= 1024
  scan_chunks<<<nblk, 256, 0, stream>>>(deg, N, scanned, partials);
  scan_partials<<<1, 1024, 0, stream>>>(partials, nblk);
  finalize_rowptr<<<nblk, 256, 0, stream>>>(scanned, partials, deg, N, row_ptr,
                                            cursor);

  const int rows_per_tile = (N + NTILE - 1) / NTILE;  // 18750
  const int blocks_per_tile = 1024;
  const int fill_stride = blocks_per_tile * 256;
  fill_csr_tiled<<<blocks_per_tile * NTILE, 256, 0, stream>>>(
      adj_rows, adj_cols, adj_vals, nnz, rows_per_tile, fill_stride, cursor,
      csr);

  const int rblocks = (N + 3) / 4;  // 4 waves (rows) per block
  spmm_l1<<<rblocks, 256, 0, stream>>>(row_ptr, csr, user_emb, item_emb, U,
                                       x1, N);
  spmm4<<<rblocks, 256, 0, stream>>>(row_ptr, csr, x1, x2, N);

  spmm3_score<<<(B + 3) / 4, 256, 0, stream>>>(row_ptr, csr, user_emb,
                                               item_emb, x1, x2, user_ids,
                                               item_ids, U, B, scores);
}

// Round 4
// 577.753 us; speedup vs baseline: 2.2956x; 1.0499x over previous
//
#include <hip/hip_runtime.h>

// LightGCN on MI355X — round 3.
// CSR build rewritten as LDS-staged two-phase partition (multisplit):
//   hist_deg -> fused scan(deg|hist) -> partition_edges (coalesced bucket
//   writes) -> build_csr (L2-resident per-tile scatter).
// SpMM layers 1-2 + fused layer-3 scorer unchanged from R2.

#define DIM 64
#define PW 1024          // partition workgroups
#define TSHIFT 10        // 1024 rows per tile
#define STAGE_CAP 3328   // >= ceil(nnz/PW) = 3125

__global__ __launch_bounds__(256) void hist_deg(
    const int* __restrict__ rows, int nnz, int ewg, int T,
    int* __restrict__ deg, int* __restrict__ hist_g) {
  __shared__ int h[256];
  int w = blockIdx.x, tid = threadIdx.x;
  h[tid] = 0;
  __syncthreads();
  int base = w * ewg;
  int end = min(base + ewg, nnz);
  for (int e = base + tid; e < end; e += 256) {
    int r = rows[e];
    atomicAdd(&deg[r], 1);
    atomicAdd(&h[r >> TSHIFT], 1);
  }
  __syncthreads();
  if (tid < T) hist_g[tid * PW + w] = h[tid];  // tile-major
}

// inclusive scan of 512-element chunks
__global__ __launch_bounds__(512) void scan_chunks512(
    const int* __restrict__ in, int n, int* __restrict__ scanned,
    int* __restrict__ partials) {
  __shared__ int s[512];
  int t = threadIdx.x;
  int g = blockIdx.x * 512 + t;
  s[t] = (g < n) ? in[g] : 0;
  __syncthreads();
  for (int off = 1; off < 512; off <<= 1) {
    int v = (t >= off) ? s[t - off] : 0;
    __syncthreads();
    s[t] += v;
    __syncthreads();
  }
  if (g < n) scanned[g] = s[t];
  if (t == 511) partials[blockIdx.x] = s[511];
}

__global__ __launch_bounds__(1024) void scan_partials(
    int* __restrict__ partials, int nblk) {
  __shared__ int s[1024];
  int t = threadIdx.x;
  s[t] = (t < nblk) ? partials[t] : 0;
  __syncthreads();
  for (int off = 1; off < 1024; off <<= 1) {
    int v = (t >= off) ? s[t - off] : 0;
    __syncthreads();
    s[t] += v;
    __syncthreads();
  }
  if (t < nblk) partials[t] = (t == 0) ? 0 : s[t - 1];
}

// g < N: row_ptr[g+1]=incl, cursor[g]=incl-deg.  g >= N: hist part ->
// offs[h] = (incl - nnz) - hist[h]  (exclusive, tile-major).
__global__ __launch_bounds__(512) void finalize_all(
    const int* __restrict__ scanned, const int* __restrict__ partials,
    const int* __restrict__ src, int N, int total, int nnz,
    int* __restrict__ row_ptr, int* __restrict__ cursor,
    int* __restrict__ offs) {
  int g = blockIdx.x * 512 + threadIdx.x;
  if (g >= total) return;
  int incl = scanned[g] + partials[blockIdx.x];
  if (g < N) {
    row_ptr[g + 1] = incl;
    cursor[g] = incl - src[g];
    if (g == 0) row_ptr[0] = 0;
  } else {
    offs[g - N] = incl - src[g] - nnz;
  }
}

// each wg: stage its ~3125 bucket entries in LDS (counting-sorted by tile),
// then flush coalesced into per-(tile,wg) contiguous global runs.
__global__ __launch_bounds__(256) void partition_edges(
    const int* __restrict__ rows, const int* __restrict__ cols,
    const float* __restrict__ vals, int nnz, int ewg, int T,
    const int* __restrict__ hist_g, const int* __restrict__ offs,
    int2* __restrict__ bucket) {
  __shared__ int cnt[256], lstart[256], gbase[256], cur[256], sc[256];
  __shared__ int2 stage[STAGE_CAP];
  int w = blockIdx.x, tid = threadIdx.x;
  int c = 0, gb = 0;
  if (tid < T) {
    c = hist_g[tid * PW + w];
    gb = offs[tid * PW + w];
  }
  cnt[tid] = c;
  gbase[tid] = gb;
  cur[tid] = 0;
  sc[tid] = c;
  __syncthreads();
  for (int off = 1; off < 256; off <<= 1) {
    int v = (tid >= off) ? sc[tid - off] : 0;
    __syncthreads();
    sc[tid] += v;
    __syncthreads();
  }
  lstart[tid] = sc[tid] - c;
  __syncthreads();
  int base = w * ewg;
  int end = min(base + ewg, nnz);
  for (int e = base + tid; e < end; e += 256) {
    int r = rows[e];
    int cc = cols[e];
    float fv = vals[e];
    int t = r >> TSHIFT;
    int slot = atomicAdd(&cur[t], 1);
    stage[lstart[t] + slot] =
        make_int2(((r & ((1 << TSHIFT) - 1)) << 18) | cc, __float_as_int(fv));
  }
  __syncthreads();
  for (int t = 0; t < T; ++t) {
    int n = cnt[t];
    int l0 = lstart[t];
    int g0 = gbase[t];
    for (int i = tid; i < n; i += 256) bucket[g0 + i] = stage[l0 + i];
  }
}

// per-tile scatter: bucket segment (~174 KB) and CSR window (~174 KB) both
// L2-resident. block index encodes (xcd-residue, chunk, tile-group) so a
// tile's 8 chunks share an XCD residue.
__global__ __launch_bounds__(256) void build_csr(
    const int2* __restrict__ bucket, const int* __restrict__ offs, int T,
    int nnz, int* __restrict__ cursor, int2* __restrict__ csr) {
  int b = blockIdx.x;
  int xcd = b & 7;
  int q = b >> 3;
  int chunk = q & 7;
  int tg = q >> 3;
  int t = tg * 8 + xcd;
  if (t >= T) return;
  int tstart = offs[t * PW];
  int tend = (t + 1 < T) ? offs[(t + 1) * PW] : nnz;
  int len = tend - tstart;
  int lo = tstart + (int)(((long long)len * chunk) >> 3);
  int hi = tstart + (int)(((long long)len * (chunk + 1)) >> 3);
  int rbase = t << TSHIFT;
  for (int e = lo + threadIdx.x; e < hi; e += 256) {
    int2 ent = bucket[e];
    int row = rbase + (ent.x >> 18);
    int col = ent.x & 0x3FFFF;
    int p = atomicAdd(&cursor[row], 1);
    csr[p] = make_int2(col, ent.y);
  }
}

// one wave per row; 4 sub-groups x 16 lanes; float4 per lane; unroll x2.
__global__ __launch_bounds__(256) void spmm_l1(
    const int* __restrict__ row_ptr, const int2* __restrict__ csr,
    const float* __restrict__ ue, const float* __restrict__ ie, int U,
    float* __restrict__ x_out, int n) {
  int w = (blockIdx.x * 256 + threadIdx.x) >> 6;
  int lane = threadIdx.x & 63;
  if (w >= n) return;
  int s = lane >> 4;
  int d4 = (lane & 15) * 4;
  int start = row_ptr[w];
  int end = row_ptr[w + 1];
  float4 sum = {0.f, 0.f, 0.f, 0.f};
  for (int k = start + s; k < end; k += 8) {
    int k2 = k + 4;
    bool ok2 = k2 < end;
    int2 cv0 = csr[k];
    int2 cv1 = csr[ok2 ? k2 : k];
    int c0 = cv0.x, c1 = cv1.x;
    const float* p0 = (c0 < U) ? (ue + (size_t)c0 * DIM)
                               : (ie + (size_t)(c0 - U) * DIM);
    const float* p1 = (c1 < U) ? (ue + (size_t)c1 * DIM)
                               : (ie + (size_t)(c1 - U) * DIM);
    float4 g0 = *(const float4*)(p0 + d4);
    float4 g1 = *(const float4*)(p1 + d4);
    float v0 = __int_as_float(cv0.y);
    float v1 = ok2 ? __int_as_float(cv1.y) : 0.f;
    sum.x += v0 * g0.x; sum.y += v0 * g0.y;
    sum.z += v0 * g0.z; sum.w += v0 * g0.w;
    sum.x += v1 * g1.x; sum.y += v1 * g1.y;
    sum.z += v1 * g1.z; sum.w += v1 * g1.w;
  }
  sum.x += __shfl_xor(sum.x, 16, 64); sum.y += __shfl_xor(sum.y, 16, 64);
  sum.z += __shfl_xor(sum.z, 16, 64); sum.w += __shfl_xor(sum.w, 16, 64);
  sum.x += __shfl_xor(sum.x, 32, 64); sum.y += __shfl_xor(sum.y, 32, 64);
  sum.z += __shfl_xor(sum.z, 32, 64); sum.w += __shfl_xor(sum.w, 32, 64);
  if (lane < 16) *(float4*)(x_out + (size_t)w * DIM + d4) = sum;
}

__global__ __launch_bounds__(256) void spmm4(
    const int* __restrict__ row_ptr, const int2* __restrict__ csr,
    const float* __restrict__ x_in, float* __restrict__ x_out, int n) {
  int w = (blockIdx.x * 256 + threadIdx.x) >> 6;
  int lane = threadIdx.x & 63;
  if (w >= n) return;
  int s = lane >> 4;
  int d4 = (lane & 15) * 4;
  int start = row_ptr[w];
  int end = row_ptr[w + 1];
  float4 sum = {0.f, 0.f, 0.f, 0.f};
  for (int k = start + s; k < end; k += 8) {
    int k2 = k + 4;
    bool ok2 = k2 < end;
    int2 cv0 = csr[k];
    int2 cv1 = csr[ok2 ? k2 : k];
    float4 g0 = *(const float4*)(x_in + (size_t)cv0.x * DIM + d4);
    float4 g1 = *(const float4*)(x_in + (size_t)cv1.x * DIM + d4);
    float v0 = __int_as_float(cv0.y);
    float v1 = ok2 ? __int_as_float(cv1.y) : 0.f;
    sum.x += v0 * g0.x; sum.y += v0 * g0.y;
    sum.z += v0 * g0.z; sum.w += v0 * g0.w;
    sum.x += v1 * g1.x; sum.y += v1 * g1.y;
    sum.z += v1 * g1.z; sum.w += v1 * g1.w;
  }
  sum.x += __shfl_xor(sum.x, 16, 64); sum.y += __shfl_xor(sum.y, 16, 64);
  sum.z += __shfl_xor(sum.z, 16, 64); sum.w += __shfl_xor(sum.w, 16, 64);
  sum.x += __shfl_xor(sum.x, 32, 64); sum.y += __shfl_xor(sum.y, 32, 64);
  sum.z += __shfl_xor(sum.z, 32, 64); sum.w += __shfl_xor(sum.w, 32, 64);
  if (lane < 16) *(float4*)(x_out + (size_t)w * DIM + d4) = sum;
}

__device__ __forceinline__ float4 gather_row(
    const int* __restrict__ row_ptr, const int2* __restrict__ csr,
    const float* __restrict__ x, int row, int s, int d4) {
  int start = row_ptr[row];
  int end = row_ptr[row + 1];
  float4 sum = {0.f, 0.f, 0.f, 0.f};
  for (int k = start + s; k < end; k += 8) {
    int k2 = k + 4;
    bool ok2 = k2 < end;
    int2 cv0 = csr[k];
    int2 cv1 = csr[ok2 ? k2 : k];
    float4 g0 = *(const float4*)(x + (size_t)cv0.x * DIM + d4);
    float4 g1 = *(const float4*)(x + (size_t)cv1.x * DIM + d4);
    float v0 = __int_as_float(cv0.y);
    float v1 = ok2 ? __int_as_float(cv1.y) : 0.f;
    sum.x += v0 * g0.x; sum.y += v0 * g0.y;
    sum.z += v0 * g0.z; sum.w += v0 * g0.w;
    sum.x += v1 * g1.x; sum.y += v1 * g1.y;
    sum.z += v1 * g1.z; sum.w += v1 * g1.w;
  }
  sum.x += __shfl_xor(sum.x, 16, 64); sum.y += __shfl_xor(sum.y, 16, 64);
  sum.z += __shfl_xor(sum.z, 16, 64); sum.w += __shfl_xor(sum.w, 16, 64);
  sum.x += __shfl_xor(sum.x, 32, 64); sum.y += __shfl_xor(sum.y, 32, 64);
  sum.z += __shfl_xor(sum.z, 32, 64); sum.w += __shfl_xor(sum.w, 32, 64);
  return sum;
}

__global__ __launch_bounds__(256) void spmm3_score(
    const int* __restrict__ row_ptr, const int2* __restrict__ csr,
    const float* __restrict__ ue, const float* __restrict__ ie,
    const float* __restrict__ x1, const float* __restrict__ x2,
    const int* __restrict__ user_ids, const int* __restrict__ item_ids,
    int U, int batch, float* __restrict__ out) {
  int w = (blockIdx.x * 256 + threadIdx.x) >> 6;
  int lane = threadIdx.x & 63;
  if (w >= batch) return;
  int s = lane >> 4;
  int d4 = (lane & 15) * 4;
  int q = lane & 15;
  int u = user_ids[w];
  int iti = item_ids[w];
  int it = iti + U;
  float4 x3u = gather_row(row_ptr, csr, x2, u, s, d4);
  float4 x3i = gather_row(row_ptr, csr, x2, it, s, d4);
  float4 a0 = ((const float4*)ue)[(size_t)u * 16 + q];
  float4 b0 = ((const float4*)ie)[(size_t)iti * 16 + q];
  float4 a1 = ((const float4*)x1)[(size_t)u * 16 + q];
  float4 b1 = ((const float4*)x1)[(size_t)it * 16 + q];
  float4 a2 = ((const float4*)x2)[(size_t)u * 16 + q];
  float4 b2 = ((const float4*)x2)[(size_t)it * 16 + q];
  float ax = a0.x + a1.x + a2.x + x3u.x;
  float ay = a0.y + a1.y + a2.y + x3u.y;
  float az = a0.z + a1.z + a2.z + x3u.z;
  float aw = a0.w + a1.w + a2.w + x3u.w;
  float bx = b0.x + b1.x + b2.x + x3i.x;
  float by = b0.y + b1.y + b2.y + x3i.y;
  float bz = b0.z + b1.z + b2.z + x3i.z;
  float bw = b0.w + b1.w + b2.w + x3i.w;
  float p = ax * bx + ay * by + az * bz + aw * bw;
  p += __shfl_xor(p, 1, 64);
  p += __shfl_xor(p, 2, 64);
  p += __shfl_xor(p, 4, 64);
  p += __shfl_xor(p, 8, 64);
  if (lane == 0) out[w] = p * (1.0f / 16.0f);
}

extern "C" void kernel_launch(void* const* d_in, const int* in_sizes, int n_in,
                              void* d_out, int out_size, void* d_ws, size_t ws_size,
                              hipStream_t stream) {
  const float* user_emb = (const float*)d_in[0];
  const float* item_emb = (const float*)d_in[1];
  const float* adj_vals = (const float*)d_in[2];
  const int* adj_rows = (const int*)d_in[3];
  const int* adj_cols = (const int*)d_in[4];
  const int* user_ids = (const int*)d_in[5];
  const int* item_ids = (const int*)d_in[6];
  float* scores = (float*)d_out;

  const int U = in_sizes[0] / DIM;  // 100000
  const int I = in_sizes[1] / DIM;  // 50000
  const int N = U + I;              // 150000
  const int nnz = in_sizes[2];      // 3200000
  const int B = in_sizes[5];        // 4096

  const int T = (N + (1 << TSHIFT) - 1) >> TSHIFT;  // 147 (must be <= 256)
  const int TW = T * PW;                            // 150528
  const int SCAN_N = N + TW;                        // 300528
  const int ewg = (nnz + PW - 1) / PW;              // 3125 (<= STAGE_CAP)

  char* p = (char*)d_ws;
  auto carve = [&](size_t bytes) {
    void* r = (void*)p;
    p += (bytes + 255) & ~(size_t)255;
    return r;
  };
  float* x1 = (float*)carve((size_t)N * DIM * 4);
  float* x2 = (float*)carve((size_t)N * DIM * 4);
  int* scanbuf = (int*)carve((size_t)SCAN_N * 4);  // [deg(N) | hist(T*PW)]
  int* scanned = (int*)carve((size_t)SCAN_N * 4);
  int* partials = (int*)carve((size_t)1024 * 4);
  int* row_ptr = (int*)carve((size_t)(N + 1) * 4);
  int* cursor = (int*)carve((size_t)N * 4);
  int* offs = (int*)carve((size_t)TW * 4);
  int2* bucket = (int2*)carve((size_t)nnz * 8);
  int2* csr = (int2*)carve((size_t)nnz * 8);
  int* deg = scanbuf;
  int* hist_g = scanbuf + N;

  hipMemsetAsync(deg, 0, (size_t)N * 4, stream);

  hist_deg<<<PW, 256, 0, stream>>>(adj_rows, nnz, ewg, T, deg, hist_g);

  const int nchunk = (SCAN_N + 511) / 512;  // 587 <= 1024
  scan_chunks512<<<nchunk, 512, 0, stream>>>(scanbuf, SCAN_N, scanned,
                                             partials);
  scan_partials<<<1, 1024, 0, stream>>>(partials, nchunk);
  finalize_all<<<nchunk, 512, 0, stream>>>(scanned, partials, scanbuf, N,
                                           SCAN_N, nnz, row_ptr, cursor, offs);

  partition_edges<<<PW, 256, 0, stream>>>(adj_rows, adj_cols, adj_vals, nnz,
                                          ewg, T, hist_g, offs, bucket);

  const int tgroups = (T + 7) / 8;  // 19
  build_csr<<<tgroups * 64, 256, 0, stream>>>(bucket, offs, T, nnz, cursor,
                                              csr);

  const int rblocks = (N + 3) / 4;
  spmm_l1<<<rblocks, 256, 0, stream>>>(row_ptr, csr, user_emb, item_emb, U,
                                       x1, N);
  spmm4<<<rblocks, 256, 0, stream>>>(row_ptr, csr, x1, x2, N);

  spmm3_score<<<(B + 3) / 4, 256, 0, stream>>>(row_ptr, csr, user_emb,
                                               item_emb, x1, x2, user_ids,
                                               item_ids, U, B, scores);
}

// Round 5
// 407.580 us; speedup vs baseline: 3.2540x; 1.4175x over previous
//
#include <hip/hip_runtime.h>

// LightGCN on MI355X — round 4.
//  * global deg atomics DELETED: row_ptr derived per-tile in build_csr_tile
//    (LDS histogram + LDS scan; tile segments are contiguous & row-ordered).
//  * partition flush full-width via per-entry dst addresses (was 147 serial
//    lane-starved tile loops).
//  * hist: 4 per-wave sub-histograms (4x less LDS atomic contention).
// SpMM layers 1-2 + fused layer-3 scorer unchanged.

#define DIM 64
#define PW 1024          // partition workgroups
#define TSHIFT 10        // 1024 rows per tile
#define TMASK ((1 << TSHIFT) - 1)
#define STAGE_CAP 3328   // >= ceil(nnz/PW) = 3125

__global__ __launch_bounds__(256) void hist_tiles(
    const int* __restrict__ rows, int nnz, int ewg, int T,
    int* __restrict__ hist_g) {
  __shared__ int h[4][256];
  int w = blockIdx.x, tid = threadIdx.x;
  int wv = tid >> 6;
  for (int i = tid; i < 1024; i += 256) ((int*)h)[i] = 0;
  __syncthreads();
  int base = w * ewg;
  int end = min(base + ewg, nnz);
  for (int e = base + tid; e < end; e += 256)
    atomicAdd(&h[wv][rows[e] >> TSHIFT], 1);
  __syncthreads();
  if (tid < T)
    hist_g[tid * PW + w] = h[0][tid] + h[1][tid] + h[2][tid] + h[3][tid];
}

__global__ __launch_bounds__(512) void scan_chunks512(
    const int* __restrict__ in, int n, int* __restrict__ scanned,
    int* __restrict__ partials) {
  __shared__ int s[512];
  int t = threadIdx.x;
  int g = blockIdx.x * 512 + t;
  s[t] = (g < n) ? in[g] : 0;
  __syncthreads();
  for (int off = 1; off < 512; off <<= 1) {
    int v = (t >= off) ? s[t - off] : 0;
    __syncthreads();
    s[t] += v;
    __syncthreads();
  }
  if (g < n) scanned[g] = s[t];
  if (t == 511) partials[blockIdx.x] = s[511];
}

__global__ __launch_bounds__(1024) void scan_partials(
    int* __restrict__ partials, int nblk) {
  __shared__ int s[1024];
  int t = threadIdx.x;
  s[t] = (t < nblk) ? partials[t] : 0;
  __syncthreads();
  for (int off = 1; off < 1024; off <<= 1) {
    int v = (t >= off) ? s[t - off] : 0;
    __syncthreads();
    s[t] += v;
    __syncthreads();
  }
  if (t < nblk) partials[t] = (t == 0) ? 0 : s[t - 1];
}

// offs[g] = exclusive scan of hist_g (tile-major)
__global__ __launch_bounds__(512) void finalize_offs(
    const int* __restrict__ scanned, const int* __restrict__ partials,
    const int* __restrict__ src, int n, int* __restrict__ offs) {
  int g = blockIdx.x * 512 + threadIdx.x;
  if (g < n) offs[g] = scanned[g] + partials[blockIdx.x] - src[g];
}

// stage ~3125 entries in LDS sorted by tile, record per-entry global dst at
// insert time, flush full-width (coalesced runs per (tile,wg) segment).
__global__ __launch_bounds__(256) void partition_edges(
    const int* __restrict__ rows, const int* __restrict__ cols,
    const float* __restrict__ vals, int nnz, int ewg, int T,
    const int* __restrict__ hist_g, const int* __restrict__ offs,
    int2* __restrict__ bucket) {
  __shared__ int cnt[256], lstart[256], gbase[256], cur[256], sc[256];
  __shared__ int2 stage[STAGE_CAP];
  __shared__ int dstA[STAGE_CAP];
  int w = blockIdx.x, tid = threadIdx.x;
  int c = 0, gb = 0;
  if (tid < T) {
    c = hist_g[tid * PW + w];
    gb = offs[tid * PW + w];
  }
  cnt[tid] = c;
  gbase[tid] = gb;
  cur[tid] = 0;
  sc[tid] = c;
  __syncthreads();
  for (int off = 1; off < 256; off <<= 1) {
    int v = (tid >= off) ? sc[tid - off] : 0;
    __syncthreads();
    sc[tid] += v;
    __syncthreads();
  }
  lstart[tid] = sc[tid] - c;
  __syncthreads();
  int base = w * ewg;
  int end = min(base + ewg, nnz);
  for (int e = base + tid; e < end; e += 256) {
    int r = rows[e];
    int cc = cols[e];
    float fv = vals[e];
    int t = r >> TSHIFT;
    int slot = atomicAdd(&cur[t], 1);
    int idx = lstart[t] + slot;
    stage[idx] = make_int2(((r & TMASK) << 18) | cc, __float_as_int(fv));
    dstA[idx] = gbase[t] + slot;
  }
  __syncthreads();
  int total = end - base;
  for (int i = tid; i < total; i += 256) bucket[dstA[i]] = stage[i];
}

// one block per tile: LDS histogram of local rows -> LDS scan -> write
// row_ptr (coalesced) -> scatter csr within the L2-resident tile window.
__global__ __launch_bounds__(1024) void build_csr_tile(
    const int2* __restrict__ bucket, const int* __restrict__ offs, int T,
    int N, int nnz, int* __restrict__ row_ptr, int2* __restrict__ csr) {
  __shared__ int hist[1024], sc[1024], cur[1024];
  int t = blockIdx.x;
  int tid = threadIdx.x;
  int tstart = offs[t * PW];
  int tend = (t + 1 < T) ? offs[(t + 1) * PW] : nnz;
  hist[tid] = 0;
  __syncthreads();
  for (int e = tstart + tid; e < tend; e += 1024)
    atomicAdd(&hist[bucket[e].x >> 18], 1);
  __syncthreads();
  sc[tid] = hist[tid];
  __syncthreads();
  for (int off = 1; off < 1024; off <<= 1) {
    int v = (tid >= off) ? sc[tid - off] : 0;
    __syncthreads();
    sc[tid] += v;
    __syncthreads();
  }
  int r = (t << TSHIFT) + tid;
  if (r < N) row_ptr[r + 1] = tstart + sc[tid];
  if (t == 0 && tid == 0) row_ptr[0] = 0;
  cur[tid] = tstart + sc[tid] - hist[tid];  // row start
  __syncthreads();
  for (int e = tstart + tid; e < tend; e += 1024) {
    int2 ent = bucket[e];
    int lr = ent.x >> 18;
    int p = atomicAdd(&cur[lr], 1);
    csr[p] = make_int2(ent.x & 0x3FFFF, ent.y);
  }
}

// one wave per row; 4 sub-groups x 16 lanes; float4 per lane; unroll x2.
__global__ __launch_bounds__(256) void spmm_l1(
    const int* __restrict__ row_ptr, const int2* __restrict__ csr,
    const float* __restrict__ ue, const float* __restrict__ ie, int U,
    float* __restrict__ x_out, int n) {
  int w = (blockIdx.x * 256 + threadIdx.x) >> 6;
  int lane = threadIdx.x & 63;
  if (w >= n) return;
  int s = lane >> 4;
  int d4 = (lane & 15) * 4;
  int start = row_ptr[w];
  int end = row_ptr[w + 1];
  float4 sum = {0.f, 0.f, 0.f, 0.f};
  for (int k = start + s; k < end; k += 8) {
    int k2 = k + 4;
    bool ok2 = k2 < end;
    int2 cv0 = csr[k];
    int2 cv1 = csr[ok2 ? k2 : k];
    int c0 = cv0.x, c1 = cv1.x;
    const float* p0 = (c0 < U) ? (ue + (size_t)c0 * DIM)
                               : (ie + (size_t)(c0 - U) * DIM);
    const float* p1 = (c1 < U) ? (ue + (size_t)c1 * DIM)
                               : (ie + (size_t)(c1 - U) * DIM);
    float4 g0 = *(const float4*)(p0 + d4);
    float4 g1 = *(const float4*)(p1 + d4);
    float v0 = __int_as_float(cv0.y);
    float v1 = ok2 ? __int_as_float(cv1.y) : 0.f;
    sum.x += v0 * g0.x; sum.y += v0 * g0.y;
    sum.z += v0 * g0.z; sum.w += v0 * g0.w;
    sum.x += v1 * g1.x; sum.y += v1 * g1.y;
    sum.z += v1 * g1.z; sum.w += v1 * g1.w;
  }
  sum.x += __shfl_xor(sum.x, 16, 64); sum.y += __shfl_xor(sum.y, 16, 64);
  sum.z += __shfl_xor(sum.z, 16, 64); sum.w += __shfl_xor(sum.w, 16, 64);
  sum.x += __shfl_xor(sum.x, 32, 64); sum.y += __shfl_xor(sum.y, 32, 64);
  sum.z += __shfl_xor(sum.z, 32, 64); sum.w += __shfl_xor(sum.w, 32, 64);
  if (lane < 16) *(float4*)(x_out + (size_t)w * DIM + d4) = sum;
}

__global__ __launch_bounds__(256) void spmm4(
    const int* __restrict__ row_ptr, const int2* __restrict__ csr,
    const float* __restrict__ x_in, float* __restrict__ x_out, int n) {
  int w = (blockIdx.x * 256 + threadIdx.x) >> 6;
  int lane = threadIdx.x & 63;
  if (w >= n) return;
  int s = lane >> 4;
  int d4 = (lane & 15) * 4;
  int start = row_ptr[w];
  int end = row_ptr[w + 1];
  float4 sum = {0.f, 0.f, 0.f, 0.f};
  for (int k = start + s; k < end; k += 8) {
    int k2 = k + 4;
    bool ok2 = k2 < end;
    int2 cv0 = csr[k];
    int2 cv1 = csr[ok2 ? k2 : k];
    float4 g0 = *(const float4*)(x_in + (size_t)cv0.x * DIM + d4);
    float4 g1 = *(const float4*)(x_in + (size_t)cv1.x * DIM + d4);
    float v0 = __int_as_float(cv0.y);
    float v1 = ok2 ? __int_as_float(cv1.y) : 0.f;
    sum.x += v0 * g0.x; sum.y += v0 * g0.y;
    sum.z += v0 * g0.z; sum.w += v0 * g0.w;
    sum.x += v1 * g1.x; sum.y += v1 * g1.y;
    sum.z += v1 * g1.z; sum.w += v1 * g1.w;
  }
  sum.x += __shfl_xor(sum.x, 16, 64); sum.y += __shfl_xor(sum.y, 16, 64);
  sum.z += __shfl_xor(sum.z, 16, 64); sum.w += __shfl_xor(sum.w, 16, 64);
  sum.x += __shfl_xor(sum.x, 32, 64); sum.y += __shfl_xor(sum.y, 32, 64);
  sum.z += __shfl_xor(sum.z, 32, 64); sum.w += __shfl_xor(sum.w, 32, 64);
  if (lane < 16) *(float4*)(x_out + (size_t)w * DIM + d4) = sum;
}

__device__ __forceinline__ float4 gather_row(
    const int* __restrict__ row_ptr, const int2* __restrict__ csr,
    const float* __restrict__ x, int row, int s, int d4) {
  int start = row_ptr[row];
  int end = row_ptr[row + 1];
  float4 sum = {0.f, 0.f, 0.f, 0.f};
  for (int k = start + s; k < end; k += 8) {
    int k2 = k + 4;
    bool ok2 = k2 < end;
    int2 cv0 = csr[k];
    int2 cv1 = csr[ok2 ? k2 : k];
    float4 g0 = *(const float4*)(x + (size_t)cv0.x * DIM + d4);
    float4 g1 = *(const float4*)(x + (size_t)cv1.x * DIM + d4);
    float v0 = __int_as_float(cv0.y);
    float v1 = ok2 ? __int_as_float(cv1.y) : 0.f;
    sum.x += v0 * g0.x; sum.y += v0 * g0.y;
    sum.z += v0 * g0.z; sum.w += v0 * g0.w;
    sum.x += v1 * g1.x; sum.y += v1 * g1.y;
    sum.z += v1 * g1.z; sum.w += v1 * g1.w;
  }
  sum.x += __shfl_xor(sum.x, 16, 64); sum.y += __shfl_xor(sum.y, 16, 64);
  sum.z += __shfl_xor(sum.z, 16, 64); sum.w += __shfl_xor(sum.w, 16, 64);
  sum.x += __shfl_xor(sum.x, 32, 64); sum.y += __shfl_xor(sum.y, 32, 64);
  sum.z += __shfl_xor(sum.z, 32, 64); sum.w += __shfl_xor(sum.w, 32, 64);
  return sum;
}

__global__ __launch_bounds__(256) void spmm3_score(
    const int* __restrict__ row_ptr, const int2* __restrict__ csr,
    const float* __restrict__ ue, const float* __restrict__ ie,
    const float* __restrict__ x1, const float* __restrict__ x2,
    const int* __restrict__ user_ids, const int* __restrict__ item_ids,
    int U, int batch, float* __restrict__ out) {
  int w = (blockIdx.x * 256 + threadIdx.x) >> 6;
  int lane = threadIdx.x & 63;
  if (w >= batch) return;
  int s = lane >> 4;
  int d4 = (lane & 15) * 4;
  int q = lane & 15;
  int u = user_ids[w];
  int iti = item_ids[w];
  int it = iti + U;
  float4 x3u = gather_row(row_ptr, csr, x2, u, s, d4);
  float4 x3i = gather_row(row_ptr, csr, x2, it, s, d4);
  float4 a0 = ((const float4*)ue)[(size_t)u * 16 + q];
  float4 b0 = ((const float4*)ie)[(size_t)iti * 16 + q];
  float4 a1 = ((const float4*)x1)[(size_t)u * 16 + q];
  float4 b1 = ((const float4*)x1)[(size_t)it * 16 + q];
  float4 a2 = ((const float4*)x2)[(size_t)u * 16 + q];
  float4 b2 = ((const float4*)x2)[(size_t)it * 16 + q];
  float ax = a0.x + a1.x + a2.x + x3u.x;
  float ay = a0.y + a1.y + a2.y + x3u.y;
  float az = a0.z + a1.z + a2.z + x3u.z;
  float aw = a0.w + a1.w + a2.w + x3u.w;
  float bx = b0.x + b1.x + b2.x + x3i.x;
  float by = b0.y + b1.y + b2.y + x3i.y;
  float bz = b0.z + b1.z + b2.z + x3i.z;
  float bw = b0.w + b1.w + b2.w + x3i.w;
  float p = ax * bx + ay * by + az * bz + aw * bw;
  p += __shfl_xor(p, 1, 64);
  p += __shfl_xor(p, 2, 64);
  p += __shfl_xor(p, 4, 64);
  p += __shfl_xor(p, 8, 64);
  if (lane == 0) out[w] = p * (1.0f / 16.0f);
}

extern "C" void kernel_launch(void* const* d_in, const int* in_sizes, int n_in,
                              void* d_out, int out_size, void* d_ws, size_t ws_size,
                              hipStream_t stream) {
  const float* user_emb = (const float*)d_in[0];
  const float* item_emb = (const float*)d_in[1];
  const float* adj_vals = (const float*)d_in[2];
  const int* adj_rows = (const int*)d_in[3];
  const int* adj_cols = (const int*)d_in[4];
  const int* user_ids = (const int*)d_in[5];
  const int* item_ids = (const int*)d_in[6];
  float* scores = (float*)d_out;

  const int U = in_sizes[0] / DIM;  // 100000
  const int I = in_sizes[1] / DIM;  // 50000
  const int N = U + I;              // 150000
  const int nnz = in_sizes[2];      // 3200000
  const int B = in_sizes[5];        // 4096

  const int T = (N + TMASK) >> TSHIFT;  // 147 (<= 256)
  const int TW = T * PW;                // 150528
  const int ewg = (nnz + PW - 1) / PW;  // 3125 (<= STAGE_CAP)

  char* p = (char*)d_ws;
  auto carve = [&](size_t bytes) {
    void* r = (void*)p;
    p += (bytes + 255) & ~(size_t)255;
    return r;
  };
  float* x1 = (float*)carve((size_t)N * DIM * 4);
  float* x2 = (float*)carve((size_t)N * DIM * 4);
  int* hist_g = (int*)carve((size_t)TW * 4);
  int* scanned = (int*)carve((size_t)TW * 4);
  int* partials = (int*)carve((size_t)1024 * 4);
  int* row_ptr = (int*)carve((size_t)(N + 1) * 4);
  int* offs = (int*)carve((size_t)TW * 4);
  int2* bucket = (int2*)carve((size_t)nnz * 8);
  int2* csr = (int2*)carve((size_t)nnz * 8);

  hist_tiles<<<PW, 256, 0, stream>>>(adj_rows, nnz, ewg, T, hist_g);

  const int nchunk = (TW + 511) / 512;  // 294 <= 1024
  scan_chunks512<<<nchunk, 512, 0, stream>>>(hist_g, TW, scanned, partials);
  scan_partials<<<1, 1024, 0, stream>>>(partials, nchunk);
  finalize_offs<<<nchunk, 512, 0, stream>>>(scanned, partials, hist_g, TW,
                                            offs);

  partition_edges<<<PW, 256, 0, stream>>>(adj_rows, adj_cols, adj_vals, nnz,
                                          ewg, T, hist_g, offs, bucket);

  build_csr_tile<<<T, 1024, 0, stream>>>(bucket, offs, T, N, nnz, row_ptr,
                                         csr);

  const int rblocks = (N + 3) / 4;
  spmm_l1<<<rblocks, 256, 0, stream>>>(row_ptr, csr, user_emb, item_emb, U,
                                       x1, N);
  spmm4<<<rblocks, 256, 0, stream>>>(row_ptr, csr, x1, x2, N);

  spmm3_score<<<(B + 3) / 4, 256, 0, stream>>>(row_ptr, csr, user_emb,
                                               item_emb, x1, x2, user_ids,
                                               item_ids, U, B, scores);
}

// Round 6
// 338.863 us; speedup vs baseline: 3.9139x; 1.2028x over previous
//
#include <hip/hip_runtime.h>

// LightGCN on MI355X — round 5.
// bf16 gather tables: x0 (converted from inputs) and x1 stored bf16 ->
// gathered row = 128 B (2 lines, not 4); wave = 8 edge-slots x 8 lanes
// (8 gathers in flight/instr). Accumulation + csr vals + x2 stay fp32.
// Build pipeline (hist -> scan -> partition -> build_csr_tile) unchanged.

#define DIM 64
#define PW 1024
#define TSHIFT 10
#define TMASK ((1 << TSHIFT) - 1)
#define STAGE_CAP 3328

typedef unsigned short u16;
typedef unsigned int u32;

__device__ __forceinline__ u32 f2bf(float f) {  // RNE pack to bf16 bits
  u32 u = __float_as_uint(f);
  return (u + 0x7FFFu + ((u >> 16) & 1u)) >> 16;
}
__device__ __forceinline__ float bflo(u32 u) {
  return __uint_as_float(u << 16);
}
__device__ __forceinline__ float bfhi(u32 u) {
  return __uint_as_float(u & 0xFFFF0000u);
}

// ---------------- build pipeline (unchanged from R4) ----------------

__global__ __launch_bounds__(256) void hist_tiles(
    const int* __restrict__ rows, int nnz, int ewg, int T,
    int* __restrict__ hist_g) {
  __shared__ int h[4][256];
  int w = blockIdx.x, tid = threadIdx.x;
  int wv = tid >> 6;
  for (int i = tid; i < 1024; i += 256) ((int*)h)[i] = 0;
  __syncthreads();
  int base = w * ewg;
  int end = min(base + ewg, nnz);
  for (int e = base + tid; e < end; e += 256)
    atomicAdd(&h[wv][rows[e] >> TSHIFT], 1);
  __syncthreads();
  if (tid < T)
    hist_g[tid * PW + w] = h[0][tid] + h[1][tid] + h[2][tid] + h[3][tid];
}

__global__ __launch_bounds__(512) void scan_chunks512(
    const int* __restrict__ in, int n, int* __restrict__ scanned,
    int* __restrict__ partials) {
  __shared__ int s[512];
  int t = threadIdx.x;
  int g = blockIdx.x * 512 + t;
  s[t] = (g < n) ? in[g] : 0;
  __syncthreads();
  for (int off = 1; off < 512; off <<= 1) {
    int v = (t >= off) ? s[t - off] : 0;
    __syncthreads();
    s[t] += v;
    __syncthreads();
  }
  if (g < n) scanned[g] = s[t];
  if (t == 511) partials[blockIdx.x] = s[511];
}

__global__ __launch_bounds__(1024) void scan_partials(
    int* __restrict__ partials, int nblk) {
  __shared__ int s[1024];
  int t = threadIdx.x;
  s[t] = (t < nblk) ? partials[t] : 0;
  __syncthreads();
  for (int off = 1; off < 1024; off <<= 1) {
    int v = (t >= off) ? s[t - off] : 0;
    __syncthreads();
    s[t] += v;
    __syncthreads();
  }
  if (t < nblk) partials[t] = (t == 0) ? 0 : s[t - 1];
}

__global__ __launch_bounds__(512) void finalize_offs(
    const int* __restrict__ scanned, const int* __restrict__ partials,
    const int* __restrict__ src, int n, int* __restrict__ offs) {
  int g = blockIdx.x * 512 + threadIdx.x;
  if (g < n) offs[g] = scanned[g] + partials[blockIdx.x] - src[g];
}

__global__ __launch_bounds__(256) void partition_edges(
    const int* __restrict__ rows, const int* __restrict__ cols,
    const float* __restrict__ vals, int nnz, int ewg, int T,
    const int* __restrict__ hist_g, const int* __restrict__ offs,
    int2* __restrict__ bucket) {
  __shared__ int cnt[256], lstart[256], gbase[256], cur[256], sc[256];
  __shared__ int2 stage[STAGE_CAP];
  __shared__ int dstA[STAGE_CAP];
  int w = blockIdx.x, tid = threadIdx.x;
  int c = 0, gb = 0;
  if (tid < T) {
    c = hist_g[tid * PW + w];
    gb = offs[tid * PW + w];
  }
  cnt[tid] = c;
  gbase[tid] = gb;
  cur[tid] = 0;
  sc[tid] = c;
  __syncthreads();
  for (int off = 1; off < 256; off <<= 1) {
    int v = (tid >= off) ? sc[tid - off] : 0;
    __syncthreads();
    sc[tid] += v;
    __syncthreads();
  }
  lstart[tid] = sc[tid] - c;
  __syncthreads();
  int base = w * ewg;
  int end = min(base + ewg, nnz);
  for (int e = base + tid; e < end; e += 256) {
    int r = rows[e];
    int cc = cols[e];
    float fv = vals[e];
    int t = r >> TSHIFT;
    int slot = atomicAdd(&cur[t], 1);
    int idx = lstart[t] + slot;
    stage[idx] = make_int2(((r & TMASK) << 18) | cc, __float_as_int(fv));
    dstA[idx] = gbase[t] + slot;
  }
  __syncthreads();
  int total = end - base;
  for (int i = tid; i < total; i += 256) bucket[dstA[i]] = stage[i];
}

__global__ __launch_bounds__(1024) void build_csr_tile(
    const int2* __restrict__ bucket, const int* __restrict__ offs, int T,
    int N, int nnz, int* __restrict__ row_ptr, int2* __restrict__ csr) {
  __shared__ int hist[1024], sc[1024], cur[1024];
  int t = blockIdx.x;
  int tid = threadIdx.x;
  int tstart = offs[t * PW];
  int tend = (t + 1 < T) ? offs[(t + 1) * PW] : nnz;
  hist[tid] = 0;
  __syncthreads();
  for (int e = tstart + tid; e < tend; e += 1024)
    atomicAdd(&hist[bucket[e].x >> 18], 1);
  __syncthreads();
  sc[tid] = hist[tid];
  __syncthreads();
  for (int off = 1; off < 1024; off <<= 1) {
    int v = (tid >= off) ? sc[tid - off] : 0;
    __syncthreads();
    sc[tid] += v;
    __syncthreads();
  }
  int r = (t << TSHIFT) + tid;
  if (r < N) row_ptr[r + 1] = tstart + sc[tid];
  if (t == 0 && tid == 0) row_ptr[0] = 0;
  cur[tid] = tstart + sc[tid] - hist[tid];
  __syncthreads();
  for (int e = tstart + tid; e < tend; e += 1024) {
    int2 ent = bucket[e];
    int lr = ent.x >> 18;
    int p = atomicAdd(&cur[lr], 1);
    csr[p] = make_int2(ent.x & 0x3FFFF, ent.y);
  }
}

// ---------------- bf16 x tables ----------------

// pack concat(ue,ie) -> bf16 x0. one thread per uint4 (8 dims).
__global__ __launch_bounds__(256) void convert_x0(
    const float4* __restrict__ ue, const float4* __restrict__ ie, int U,
    int n8, uint4* __restrict__ x0b) {
  int i = blockIdx.x * 256 + threadIdx.x;
  if (i >= n8) return;
  int row = i >> 3, q = i & 7;
  const float4* src = (row < U) ? (ue + (size_t)row * 16 + q * 2)
                                : (ie + (size_t)(row - U) * 16 + q * 2);
  float4 a = src[0], b = src[1];
  uint4 o;
  o.x = f2bf(a.x) | (f2bf(a.y) << 16);
  o.y = f2bf(a.z) | (f2bf(a.w) << 16);
  o.z = f2bf(b.x) | (f2bf(b.y) << 16);
  o.w = f2bf(b.z) | (f2bf(b.w) << 16);
  x0b[i] = o;
}

// ---------------- SpMM: 8 edge-slots x 8 lanes, bf16 gather ----------------

#define SPMM_BODY(XIN)                                                       \
  int w = (blockIdx.x * 256 + threadIdx.x) >> 6;                             \
  int lane = threadIdx.x & 63;                                               \
  if (w >= n) return;                                                        \
  int s = lane >> 3;                                                         \
  int q8 = lane & 7;                                                         \
  int start = row_ptr[w];                                                    \
  int end = row_ptr[w + 1];                                                  \
  float s0 = 0.f, s1 = 0.f, s2 = 0.f, s3 = 0.f;                              \
  float s4 = 0.f, s5 = 0.f, s6 = 0.f, s7 = 0.f;                              \
  for (int k = start + s; k < end; k += 16) {                                \
    int k2 = k + 8;                                                          \
    bool ok2 = k2 < end;                                                     \
    int2 cv0 = csr[k];                                                       \
    int2 cv1 = csr[ok2 ? k2 : k];                                            \
    uint4 g0 = ((const uint4*)(XIN + (size_t)cv0.x * DIM))[q8];              \
    uint4 g1 = ((const uint4*)(XIN + (size_t)cv1.x * DIM))[q8];              \
    float v0 = __int_as_float(cv0.y);                                        \
    float v1 = ok2 ? __int_as_float(cv1.y) : 0.f;                            \
    s0 += v0 * bflo(g0.x); s1 += v0 * bfhi(g0.x);                            \
    s2 += v0 * bflo(g0.y); s3 += v0 * bfhi(g0.y);                            \
    s4 += v0 * bflo(g0.z); s5 += v0 * bfhi(g0.z);                            \
    s6 += v0 * bflo(g0.w); s7 += v0 * bfhi(g0.w);                            \
    s0 += v1 * bflo(g1.x); s1 += v1 * bfhi(g1.x);                            \
    s2 += v1 * bflo(g1.y); s3 += v1 * bfhi(g1.y);                            \
    s4 += v1 * bflo(g1.z); s5 += v1 * bfhi(g1.z);                            \
    s6 += v1 * bflo(g1.w); s7 += v1 * bfhi(g1.w);                            \
  }                                                                          \
  for (int m = 8; m <= 32; m <<= 1) {                                        \
    s0 += __shfl_xor(s0, m, 64); s1 += __shfl_xor(s1, m, 64);                \
    s2 += __shfl_xor(s2, m, 64); s3 += __shfl_xor(s3, m, 64);                \
    s4 += __shfl_xor(s4, m, 64); s5 += __shfl_xor(s5, m, 64);                \
    s6 += __shfl_xor(s6, m, 64); s7 += __shfl_xor(s7, m, 64);                \
  }

// bf16 in -> bf16 out (layer 1)
__global__ __launch_bounds__(256) void spmm_bf_bfout(
    const int* __restrict__ row_ptr, const int2* __restrict__ csr,
    const u16* __restrict__ xin, u16* __restrict__ xout, int n) {
  SPMM_BODY(xin)
  if (lane < 8) {
    uint4 o;
    o.x = f2bf(s0) | (f2bf(s1) << 16);
    o.y = f2bf(s2) | (f2bf(s3) << 16);
    o.z = f2bf(s4) | (f2bf(s5) << 16);
    o.w = f2bf(s6) | (f2bf(s7) << 16);
    ((uint4*)(xout + (size_t)w * DIM))[lane] = o;
  }
}

// bf16 in -> fp32 out (layer 2; x2 feeds score exactly)
__global__ __launch_bounds__(256) void spmm_bf_f32out(
    const int* __restrict__ row_ptr, const int2* __restrict__ csr,
    const u16* __restrict__ xin, float* __restrict__ xout, int n) {
  SPMM_BODY(xin)
  if (lane < 8) {
    float4 o0 = {s0, s1, s2, s3};
    float4 o1 = {s4, s5, s6, s7};
    float4* dst = (float4*)(xout + (size_t)w * DIM) + lane * 2;
    dst[0] = o0;
    dst[1] = o1;
  }
}

// ---------------- fused layer-3 + scorer (16-lane fp32 layout) -------------

__device__ __forceinline__ float4 gather_row_f32(
    const int* __restrict__ row_ptr, const int2* __restrict__ csr,
    const float* __restrict__ x, int row, int s, int d4) {
  int start = row_ptr[row];
  int end = row_ptr[row + 1];
  float4 sum = {0.f, 0.f, 0.f, 0.f};
  for (int k = start + s; k < end; k += 8) {
    int k2 = k + 4;
    bool ok2 = k2 < end;
    int2 cv0 = csr[k];
    int2 cv1 = csr[ok2 ? k2 : k];
    float4 g0 = *(const float4*)(x + (size_t)cv0.x * DIM + d4);
    float4 g1 = *(const float4*)(x + (size_t)cv1.x * DIM + d4);
    float v0 = __int_as_float(cv0.y);
    float v1 = ok2 ? __int_as_float(cv1.y) : 0.f;
    sum.x += v0 * g0.x; sum.y += v0 * g0.y;
    sum.z += v0 * g0.z; sum.w += v0 * g0.w;
    sum.x += v1 * g1.x; sum.y += v1 * g1.y;
    sum.z += v1 * g1.z; sum.w += v1 * g1.w;
  }
  sum.x += __shfl_xor(sum.x, 16, 64); sum.y += __shfl_xor(sum.y, 16, 64);
  sum.z += __shfl_xor(sum.z, 16, 64); sum.w += __shfl_xor(sum.w, 16, 64);
  sum.x += __shfl_xor(sum.x, 32, 64); sum.y += __shfl_xor(sum.y, 32, 64);
  sum.z += __shfl_xor(sum.z, 32, 64); sum.w += __shfl_xor(sum.w, 32, 64);
  return sum;
}

__device__ __forceinline__ float4 ld_bf4(const u16* p) {
  uint2 t = *(const uint2*)p;
  float4 r;
  r.x = bflo(t.x); r.y = bfhi(t.x);
  r.z = bflo(t.y); r.w = bfhi(t.y);
  return r;
}

__global__ __launch_bounds__(256) void spmm3_score(
    const int* __restrict__ row_ptr, const int2* __restrict__ csr,
    const float* __restrict__ ue, const float* __restrict__ ie,
    const u16* __restrict__ x1b, const float* __restrict__ x2,
    const int* __restrict__ user_ids, const int* __restrict__ item_ids,
    int U, int batch, float* __restrict__ out) {
  int w = (blockIdx.x * 256 + threadIdx.x) >> 6;
  int lane = threadIdx.x & 63;
  if (w >= batch) return;
  int s = lane >> 4;
  int d4 = (lane & 15) * 4;
  int q = lane & 15;
  int u = user_ids[w];
  int iti = item_ids[w];
  int it = iti + U;
  float4 x3u = gather_row_f32(row_ptr, csr, x2, u, s, d4);
  float4 x3i = gather_row_f32(row_ptr, csr, x2, it, s, d4);
  float4 a0 = ((const float4*)ue)[(size_t)u * 16 + q];
  float4 b0 = ((const float4*)ie)[(size_t)iti * 16 + q];
  float4 a1 = ld_bf4(x1b + (size_t)u * DIM + d4);
  float4 b1 = ld_bf4(x1b + (size_t)it * DIM + d4);
  float4 a2 = ((const float4*)x2)[(size_t)u * 16 + q];
  float4 b2 = ((const float4*)x2)[(size_t)it * 16 + q];
  float ax = a0.x + a1.x + a2.x + x3u.x;
  float ay = a0.y + a1.y + a2.y + x3u.y;
  float az = a0.z + a1.z + a2.z + x3u.z;
  float aw = a0.w + a1.w + a2.w + x3u.w;
  float bx = b0.x + b1.x + b2.x + x3i.x;
  float by = b0.y + b1.y + b2.y + x3i.y;
  float bz = b0.z + b1.z + b2.z + x3i.z;
  float bw = b0.w + b1.w + b2.w + x3i.w;
  float p = ax * bx + ay * by + az * bz + aw * bw;
  p += __shfl_xor(p, 1, 64);
  p += __shfl_xor(p, 2, 64);
  p += __shfl_xor(p, 4, 64);
  p += __shfl_xor(p, 8, 64);
  if (lane == 0) out[w] = p * (1.0f / 16.0f);
}

extern "C" void kernel_launch(void* const* d_in, const int* in_sizes, int n_in,
                              void* d_out, int out_size, void* d_ws, size_t ws_size,
                              hipStream_t stream) {
  const float* user_emb = (const float*)d_in[0];
  const float* item_emb = (const float*)d_in[1];
  const float* adj_vals = (const float*)d_in[2];
  const int* adj_rows = (const int*)d_in[3];
  const int* adj_cols = (const int*)d_in[4];
  const int* user_ids = (const int*)d_in[5];
  const int* item_ids = (const int*)d_in[6];
  float* scores = (float*)d_out;

  const int U = in_sizes[0] / DIM;  // 100000
  const int I = in_sizes[1] / DIM;  // 50000
  const int N = U + I;              // 150000
  const int nnz = in_sizes[2];      // 3200000
  const int B = in_sizes[5];        // 4096

  const int T = (N + TMASK) >> TSHIFT;  // 147
  const int TW = T * PW;
  const int ewg = (nnz + PW - 1) / PW;  // 3125

  char* p = (char*)d_ws;
  auto carve = [&](size_t bytes) {
    void* r = (void*)p;
    p += (bytes + 255) & ~(size_t)255;
    return r;
  };
  float* x2 = (float*)carve((size_t)N * DIM * 4);
  u16* x0b = (u16*)carve((size_t)N * DIM * 2);
  u16* x1b = (u16*)carve((size_t)N * DIM * 2);
  int* hist_g = (int*)carve((size_t)TW * 4);
  int* scanned = (int*)carve((size_t)TW * 4);
  int* partials = (int*)carve((size_t)1024 * 4);
  int* row_ptr = (int*)carve((size_t)(N + 1) * 4);
  int* offs = (int*)carve((size_t)TW * 4);
  int2* bucket = (int2*)carve((size_t)nnz * 8);
  int2* csr = (int2*)carve((size_t)nnz * 8);

  // build pipeline
  hist_tiles<<<PW, 256, 0, stream>>>(adj_rows, nnz, ewg, T, hist_g);
  const int nchunk = (TW + 511) / 512;
  scan_chunks512<<<nchunk, 512, 0, stream>>>(hist_g, TW, scanned, partials);
  scan_partials<<<1, 1024, 0, stream>>>(partials, nchunk);
  finalize_offs<<<nchunk, 512, 0, stream>>>(scanned, partials, hist_g, TW,
                                            offs);
  partition_edges<<<PW, 256, 0, stream>>>(adj_rows, adj_cols, adj_vals, nnz,
                                          ewg, T, hist_g, offs, bucket);
  build_csr_tile<<<T, 1024, 0, stream>>>(bucket, offs, T, N, nnz, row_ptr,
                                         csr);

  // bf16 x0 (overlaps with build on the same stream order; independent data)
  const int n8 = N * 8;
  convert_x0<<<(n8 + 255) / 256, 256, 0, stream>>>(
      (const float4*)user_emb, (const float4*)item_emb, U, n8, (uint4*)x0b);

  const int rblocks = (N + 3) / 4;
  spmm_bf_bfout<<<rblocks, 256, 0, stream>>>(row_ptr, csr, x0b, x1b, N);
  spmm_bf_f32out<<<rblocks, 256, 0, stream>>>(row_ptr, csr, x1b, x2, N);

  spmm3_score<<<(B + 3) / 4, 256, 0, stream>>>(row_ptr, csr, user_emb,
                                               item_emb, x1b, x2, user_ids,
                                               item_ids, U, B, scores);
}

// Round 7
// 312.628 us; speedup vs baseline: 4.2423x; 1.0839x over previous
//
#include <hip/hip_runtime.h>

// LightGCN on MI355X — round 6.
// Key change: A = D^-1/2 Ā D^-1/2 is separable -> store y_l = D^-1/2 x_l and
// each layer is a pure gather-SUM: y_{l+1}[r] = (Σ_c y_l[c]) / max(deg_r,1).
//   * adj_vals never read; CSR/bucket entries are 4 B (col only) -> ~90 MB
//     less traffic across partition/build/3 spmm streams.
//   * deg derived from row_ptr diffs; score rescales x_l = sqrt(deg)*y_l.
//   * zero sentinel row N in each y table absorbs the odd-tail gather slot.
// All y tables bf16. Build pipeline structure unchanged otherwise.

#define DIM 64
#define PW 1024
#define TSHIFT 10
#define TMASK ((1 << TSHIFT) - 1)
#define STAGE_CAP 3328

typedef unsigned short u16;
typedef unsigned int u32;

__device__ __forceinline__ u32 f2bf(float f) {  // RNE pack to bf16 bits
  u32 u = __float_as_uint(f);
  return (u + 0x7FFFu + ((u >> 16) & 1u)) >> 16;
}
__device__ __forceinline__ float bflo(u32 u) {
  return __uint_as_float(u << 16);
}
__device__ __forceinline__ float bfhi(u32 u) {
  return __uint_as_float(u & 0xFFFF0000u);
}

// ---------------- build pipeline ----------------

__global__ __launch_bounds__(256) void hist_tiles(
    const int* __restrict__ rows, int nnz, int ewg, int T,
    int* __restrict__ hist_g) {
  __shared__ int h[4][256];
  int w = blockIdx.x, tid = threadIdx.x;
  int wv = tid >> 6;
  for (int i = tid; i < 1024; i += 256) ((int*)h)[i] = 0;
  __syncthreads();
  int base = w * ewg;
  int end = min(base + ewg, nnz);
  for (int e = base + tid; e < end; e += 256)
    atomicAdd(&h[wv][rows[e] >> TSHIFT], 1);
  __syncthreads();
  if (tid < T)
    hist_g[tid * PW + w] = h[0][tid] + h[1][tid] + h[2][tid] + h[3][tid];
}

__global__ __launch_bounds__(512) void scan_chunks512(
    const int* __restrict__ in, int n, int* __restrict__ scanned,
    int* __restrict__ partials) {
  __shared__ int s[512];
  int t = threadIdx.x;
  int g = blockIdx.x * 512 + t;
  s[t] = (g < n) ? in[g] : 0;
  __syncthreads();
  for (int off = 1; off < 512; off <<= 1) {
    int v = (t >= off) ? s[t - off] : 0;
    __syncthreads();
    s[t] += v;
    __syncthreads();
  }
  if (g < n) scanned[g] = s[t];
  if (t == 511) partials[blockIdx.x] = s[511];
}

__global__ __launch_bounds__(1024) void scan_partials(
    int* __restrict__ partials, int nblk) {
  __shared__ int s[1024];
  int t = threadIdx.x;
  s[t] = (t < nblk) ? partials[t] : 0;
  __syncthreads();
  for (int off = 1; off < 1024; off <<= 1) {
    int v = (t >= off) ? s[t - off] : 0;
    __syncthreads();
    s[t] += v;
    __syncthreads();
  }
  if (t < nblk) partials[t] = (t == 0) ? 0 : s[t - 1];
}

__global__ __launch_bounds__(512) void finalize_offs(
    const int* __restrict__ scanned, const int* __restrict__ partials,
    const int* __restrict__ src, int n, int* __restrict__ offs) {
  int g = blockIdx.x * 512 + threadIdx.x;
  if (g < n) offs[g] = scanned[g] + partials[blockIdx.x] - src[g];
}

// stage ~3125 4-byte entries in LDS sorted by tile; flush full-width.
__global__ __launch_bounds__(256) void partition_edges(
    const int* __restrict__ rows, const int* __restrict__ cols, int nnz,
    int ewg, int T, const int* __restrict__ hist_g,
    const int* __restrict__ offs, u32* __restrict__ bucket) {
  __shared__ int cnt[256], lstart[256], gbase[256], cur[256], sc[256];
  __shared__ u32 stage[STAGE_CAP];
  __shared__ int dstA[STAGE_CAP];
  int w = blockIdx.x, tid = threadIdx.x;
  int c = 0, gb = 0;
  if (tid < T) {
    c = hist_g[tid * PW + w];
    gb = offs[tid * PW + w];
  }
  cnt[tid] = c;
  gbase[tid] = gb;
  cur[tid] = 0;
  sc[tid] = c;
  __syncthreads();
  for (int off = 1; off < 256; off <<= 1) {
    int v = (tid >= off) ? sc[tid - off] : 0;
    __syncthreads();
    sc[tid] += v;
    __syncthreads();
  }
  lstart[tid] = sc[tid] - c;
  __syncthreads();
  int base = w * ewg;
  int end = min(base + ewg, nnz);
  for (int e = base + tid; e < end; e += 256) {
    int r = rows[e];
    int cc = cols[e];
    int t = r >> TSHIFT;
    int slot = atomicAdd(&cur[t], 1);
    int idx = lstart[t] + slot;
    stage[idx] = ((u32)(r & TMASK) << 18) | (u32)cc;
    dstA[idx] = gbase[t] + slot;
  }
  __syncthreads();
  int total = end - base;
  for (int i = tid; i < total; i += 256) bucket[dstA[i]] = stage[i];
}

// one block per tile: LDS hist+scan -> row_ptr, scatter col-only csr.
__global__ __launch_bounds__(1024) void build_csr_tile(
    const u32* __restrict__ bucket, const int* __restrict__ offs, int T,
    int N, int nnz, int* __restrict__ row_ptr, u32* __restrict__ csr) {
  __shared__ int hist[1024], sc[1024], cur[1024];
  int t = blockIdx.x;
  int tid = threadIdx.x;
  int tstart = offs[t * PW];
  int tend = (t + 1 < T) ? offs[(t + 1) * PW] : nnz;
  hist[tid] = 0;
  __syncthreads();
  for (int e = tstart + tid; e < tend; e += 1024)
    atomicAdd(&hist[bucket[e] >> 18], 1);
  __syncthreads();
  sc[tid] = hist[tid];
  __syncthreads();
  for (int off = 1; off < 1024; off <<= 1) {
    int v = (tid >= off) ? sc[tid - off] : 0;
    __syncthreads();
    sc[tid] += v;
    __syncthreads();
  }
  int r = (t << TSHIFT) + tid;
  if (r < N) row_ptr[r + 1] = tstart + sc[tid];
  if (t == 0 && tid == 0) row_ptr[0] = 0;
  cur[tid] = tstart + sc[tid] - hist[tid];
  __syncthreads();
  for (int e = tstart + tid; e < tend; e += 1024) {
    u32 ent = bucket[e];
    int p = atomicAdd(&cur[ent >> 18], 1);
    csr[p] = ent & 0x3FFFFu;
  }
}

// ---------------- y0 = D^-1/2 * concat(ue,ie), bf16; sentinel row N = 0 ----

__global__ __launch_bounds__(256) void make_y0(
    const float4* __restrict__ ue, const float4* __restrict__ ie, int U,
    int N, const int* __restrict__ row_ptr, uint4* __restrict__ y0b) {
  int i = blockIdx.x * 256 + threadIdx.x;
  int n8 = (N + 1) * 8;
  if (i >= n8) return;
  int row = i >> 3, q = i & 7;
  if (row == N) {
    y0b[i] = make_uint4(0, 0, 0, 0);
    return;
  }
  int deg = row_ptr[row + 1] - row_ptr[row];
  float invs = rsqrtf((float)max(deg, 1));
  const float4* src = (row < U) ? (ue + (size_t)row * 16 + q * 2)
                                : (ie + (size_t)(row - U) * 16 + q * 2);
  float4 a = src[0], b = src[1];
  uint4 o;
  o.x = f2bf(a.x * invs) | (f2bf(a.y * invs) << 16);
  o.y = f2bf(a.z * invs) | (f2bf(a.w * invs) << 16);
  o.z = f2bf(b.x * invs) | (f2bf(b.y * invs) << 16);
  o.w = f2bf(b.z * invs) | (f2bf(b.w * invs) << 16);
  y0b[i] = o;
}

// ---------------- SpMM: pure gather-sum, 8 slots x 8 lanes ----------------
// y_out[r] = (Σ_c y_in[c]) / max(deg_r, 1); sentinel row n absorbs odd tail.

__global__ __launch_bounds__(256) void spmm_sum(
    const int* __restrict__ row_ptr, const u32* __restrict__ csr,
    const u16* __restrict__ yin, u16* __restrict__ yout, int n) {
  if (blockIdx.x == 0 && threadIdx.x < 8)  // zero sentinel row of output
    ((uint4*)(yout + (size_t)n * DIM))[threadIdx.x] = make_uint4(0, 0, 0, 0);
  int w = (blockIdx.x * 256 + threadIdx.x) >> 6;
  int lane = threadIdx.x & 63;
  if (w >= n) return;
  int s = lane >> 3;
  int q8 = lane & 7;
  int start = row_ptr[w];
  int end = row_ptr[w + 1];
  float s0 = 0.f, s1 = 0.f, s2 = 0.f, s3 = 0.f;
  float s4 = 0.f, s5 = 0.f, s6 = 0.f, s7 = 0.f;
  for (int k = start + s; k < end; k += 16) {
    int k2 = k + 8;
    bool ok2 = k2 < end;
    u32 c0 = csr[k];
    u32 c1 = ok2 ? csr[k2] : (u32)n;  // sentinel -> adds zeros
    uint4 g0 = ((const uint4*)(yin + (size_t)c0 * DIM))[q8];
    uint4 g1 = ((const uint4*)(yin + (size_t)c1 * DIM))[q8];
    s0 += bflo(g0.x); s1 += bfhi(g0.x);
    s2 += bflo(g0.y); s3 += bfhi(g0.y);
    s4 += bflo(g0.z); s5 += bfhi(g0.z);
    s6 += bflo(g0.w); s7 += bfhi(g0.w);
    s0 += bflo(g1.x); s1 += bfhi(g1.x);
    s2 += bflo(g1.y); s3 += bfhi(g1.y);
    s4 += bflo(g1.z); s5 += bfhi(g1.z);
    s6 += bflo(g1.w); s7 += bfhi(g1.w);
  }
  for (int m = 8; m <= 32; m <<= 1) {
    s0 += __shfl_xor(s0, m, 64); s1 += __shfl_xor(s1, m, 64);
    s2 += __shfl_xor(s2, m, 64); s3 += __shfl_xor(s3, m, 64);
    s4 += __shfl_xor(s4, m, 64); s5 += __shfl_xor(s5, m, 64);
    s6 += __shfl_xor(s6, m, 64); s7 += __shfl_xor(s7, m, 64);
  }
  if (lane < 8) {
    float inv = 1.0f / (float)max(end - start, 1);
    uint4 o;
    o.x = f2bf(s0 * inv) | (f2bf(s1 * inv) << 16);
    o.y = f2bf(s2 * inv) | (f2bf(s3 * inv) << 16);
    o.z = f2bf(s4 * inv) | (f2bf(s5 * inv) << 16);
    o.w = f2bf(s6 * inv) | (f2bf(s7 * inv) << 16);
    ((uint4*)(yout + (size_t)w * DIM))[lane] = o;
  }
}

// ---------------- fused layer-3 + scorer ----------------

// gather-sum of y rows; result: o[0..7] = dims [8*q8 .. 8*q8+7], all lanes.
__device__ __forceinline__ void gather8(
    const int* __restrict__ row_ptr, const u32* __restrict__ csr,
    const u16* __restrict__ y, int row, int s, int q8, int n, float* o) {
  int start = row_ptr[row];
  int end = row_ptr[row + 1];
  float s0 = 0.f, s1 = 0.f, s2 = 0.f, s3 = 0.f;
  float s4 = 0.f, s5 = 0.f, s6 = 0.f, s7 = 0.f;
  for (int k = start + s; k < end; k += 16) {
    int k2 = k + 8;
    bool ok2 = k2 < end;
    u32 c0 = csr[k];
    u32 c1 = ok2 ? csr[k2] : (u32)n;
    uint4 g0 = ((const uint4*)(y + (size_t)c0 * DIM))[q8];
    uint4 g1 = ((const uint4*)(y + (size_t)c1 * DIM))[q8];
    s0 += bflo(g0.x); s1 += bfhi(g0.x);
    s2 += bflo(g0.y); s3 += bfhi(g0.y);
    s4 += bflo(g0.z); s5 += bfhi(g0.z);
    s6 += bflo(g0.w); s7 += bfhi(g0.w);
    s0 += bflo(g1.x); s1 += bfhi(g1.x);
    s2 += bflo(g1.y); s3 += bfhi(g1.y);
    s4 += bflo(g1.z); s5 += bfhi(g1.z);
    s6 += bflo(g1.w); s7 += bfhi(g1.w);
  }
  for (int m = 8; m <= 32; m <<= 1) {
    s0 += __shfl_xor(s0, m, 64); s1 += __shfl_xor(s1, m, 64);
    s2 += __shfl_xor(s2, m, 64); s3 += __shfl_xor(s3, m, 64);
    s4 += __shfl_xor(s4, m, 64); s5 += __shfl_xor(s5, m, 64);
    s6 += __shfl_xor(s6, m, 64); s7 += __shfl_xor(s7, m, 64);
  }
  o[0] = s0; o[1] = s1; o[2] = s2; o[3] = s3;
  o[4] = s4; o[5] = s5; o[6] = s6; o[7] = s7;
}

__global__ __launch_bounds__(256) void spmm3_score(
    const int* __restrict__ row_ptr, const u32* __restrict__ csr,
    const float* __restrict__ ue, const float* __restrict__ ie,
    const u16* __restrict__ y1b, const u16* __restrict__ y2b,
    const int* __restrict__ user_ids, const int* __restrict__ item_ids,
    int U, int N, int batch, float* __restrict__ out) {
  int w = (blockIdx.x * 256 + threadIdx.x) >> 6;
  int lane = threadIdx.x & 63;
  if (w >= batch) return;
  int s = lane >> 3;
  int q8 = lane & 7;
  int u = user_ids[w];
  int iti = item_ids[w];
  int it = iti + U;
  float gu[8], gi[8];
  gather8(row_ptr, csr, y2b, u, s, q8, N, gu);
  gather8(row_ptr, csr, y2b, it, s, q8, N, gi);
  int du = row_ptr[u + 1] - row_ptr[u];
  int di = row_ptr[it + 1] - row_ptr[it];
  float su = sqrtf((float)max(du, 1)), ru = 1.0f / su;
  float si = sqrtf((float)max(di, 1)), ri = 1.0f / si;
  // dims [8*q8, 8*q8+8)
  const float4* pu = (const float4*)(ue + (size_t)u * DIM) + q8 * 2;
  const float4* pi = (const float4*)(ie + (size_t)iti * DIM) + q8 * 2;
  float4 a0a = pu[0], a0b = pu[1];
  float4 b0a = pi[0], b0b = pi[1];
  uint4 y1u = ((const uint4*)(y1b + (size_t)u * DIM))[q8];
  uint4 y2u = ((const uint4*)(y2b + (size_t)u * DIM))[q8];
  uint4 y1i = ((const uint4*)(y1b + (size_t)it * DIM))[q8];
  uint4 y2i = ((const uint4*)(y2b + (size_t)it * DIM))[q8];
  float a[8], b[8];
  a[0] = a0a.x + su * (bflo(y1u.x) + bflo(y2u.x)) + ru * gu[0];
  a[1] = a0a.y + su * (bfhi(y1u.x) + bfhi(y2u.x)) + ru * gu[1];
  a[2] = a0a.z + su * (bflo(y1u.y) + bflo(y2u.y)) + ru * gu[2];
  a[3] = a0a.w + su * (bfhi(y1u.y) + bfhi(y2u.y)) + ru * gu[3];
  a[4] = a0b.x + su * (bflo(y1u.z) + bflo(y2u.z)) + ru * gu[4];
  a[5] = a0b.y + su * (bfhi(y1u.z) + bfhi(y2u.z)) + ru * gu[5];
  a[6] = a0b.z + su * (bflo(y1u.w) + bflo(y2u.w)) + ru * gu[6];
  a[7] = a0b.w + su * (bfhi(y1u.w) + bfhi(y2u.w)) + ru * gu[7];
  b[0] = b0a.x + si * (bflo(y1i.x) + bflo(y2i.x)) + ri * gi[0];
  b[1] = b0a.y + si * (bfhi(y1i.x) + bfhi(y2i.x)) + ri * gi[1];
  b[2] = b0a.z + si * (bflo(y1i.y) + bflo(y2i.y)) + ri * gi[2];
  b[3] = b0a.w + si * (bfhi(y1i.y) + bfhi(y2i.y)) + ri * gi[3];
  b[4] = b0b.x + si * (bflo(y1i.z) + bflo(y2i.z)) + ri * gi[4];
  b[5] = b0b.y + si * (bfhi(y1i.z) + bfhi(y2i.z)) + ri * gi[5];
  b[6] = b0b.z + si * (bflo(y1i.w) + bflo(y2i.w)) + ri * gi[6];
  b[7] = b0b.w + si * (bfhi(y1i.w) + bfhi(y2i.w)) + ri * gi[7];
  float p = 0.f;
  for (int j = 0; j < 8; ++j) p += a[j] * b[j];
  p += __shfl_xor(p, 1, 64);
  p += __shfl_xor(p, 2, 64);
  p += __shfl_xor(p, 4, 64);
  if (lane == 0) out[w] = p * (1.0f / 16.0f);
}

extern "C" void kernel_launch(void* const* d_in, const int* in_sizes, int n_in,
                              void* d_out, int out_size, void* d_ws, size_t ws_size,
                              hipStream_t stream) {
  const float* user_emb = (const float*)d_in[0];
  const float* item_emb = (const float*)d_in[1];
  const int* adj_rows = (const int*)d_in[3];
  const int* adj_cols = (const int*)d_in[4];
  const int* user_ids = (const int*)d_in[5];
  const int* item_ids = (const int*)d_in[6];
  float* scores = (float*)d_out;

  const int U = in_sizes[0] / DIM;  // 100000
  const int I = in_sizes[1] / DIM;  // 50000
  const int N = U + I;              // 150000
  const int nnz = in_sizes[2];      // 3200000
  const int B = in_sizes[5];        // 4096

  const int T = (N + TMASK) >> TSHIFT;  // 147
  const int TW = T * PW;
  const int ewg = (nnz + PW - 1) / PW;  // 3125

  char* p = (char*)d_ws;
  auto carve = [&](size_t bytes) {
    void* r = (void*)p;
    p += (bytes + 255) & ~(size_t)255;
    return r;
  };
  u16* y0b = (u16*)carve((size_t)(N + 1) * DIM * 2);
  u16* y1b = (u16*)carve((size_t)(N + 1) * DIM * 2);
  u16* y2b = (u16*)carve((size_t)(N + 1) * DIM * 2);
  int* hist_g = (int*)carve((size_t)TW * 4);
  int* scanned = (int*)carve((size_t)TW * 4);
  int* partials = (int*)carve((size_t)1024 * 4);
  int* row_ptr = (int*)carve((size_t)(N + 1) * 4);
  int* offs = (int*)carve((size_t)TW * 4);
  u32* bucket = (u32*)carve((size_t)nnz * 4);
  u32* csr = (u32*)carve((size_t)nnz * 4);

  // build pipeline
  hist_tiles<<<PW, 256, 0, stream>>>(adj_rows, nnz, ewg, T, hist_g);
  const int nchunk = (TW + 511) / 512;
  scan_chunks512<<<nchunk, 512, 0, stream>>>(hist_g, TW, scanned, partials);
  scan_partials<<<1, 1024, 0, stream>>>(partials, nchunk);
  finalize_offs<<<nchunk, 512, 0, stream>>>(scanned, partials, hist_g, TW,
                                            offs);
  partition_edges<<<PW, 256, 0, stream>>>(adj_rows, adj_cols, nnz, ewg, T,
                                          hist_g, offs, bucket);
  build_csr_tile<<<T, 1024, 0, stream>>>(bucket, offs, T, N, nnz, row_ptr,
                                         csr);

  // y0 (needs row_ptr for deg)
  const int n8 = (N + 1) * 8;
  make_y0<<<(n8 + 255) / 256, 256, 0, stream>>>(
      (const float4*)user_emb, (const float4*)item_emb, U, N, row_ptr,
      (uint4*)y0b);

  const int rblocks = (N + 3) / 4;
  spmm_sum<<<rblocks, 256, 0, stream>>>(row_ptr, csr, y0b, y1b, N);
  spmm_sum<<<rblocks, 256, 0, stream>>>(row_ptr, csr, y1b, y2b, N);

  spmm3_score<<<(B + 3) / 4, 256, 0, stream>>>(row_ptr, csr, user_emb,
                                               item_emb, y1b, y2b, user_ids,
                                               item_ids, U, N, B, scores);
}

// Round 8
// 292.981 us; speedup vs baseline: 4.5268x; 1.0671x over previous
//
#include <hip/hip_runtime.h>

// LightGCN on MI355X — round 7.
// spmm_sum restructured: one row per 8-lane group (8 rows/wave), unroll x4.
// Kills the 24-shfl butterfly epilogue (was ~55% of VALU work at deg~21).
// Memory pattern unchanged: 8 independent 128B row-gathers in flight.
// Everything else identical to R6.

#define DIM 64
#define PW 1024
#define TSHIFT 10
#define TMASK ((1 << TSHIFT) - 1)
#define STAGE_CAP 3328

typedef unsigned short u16;
typedef unsigned int u32;

__device__ __forceinline__ u32 f2bf(float f) {  // RNE pack to bf16 bits
  u32 u = __float_as_uint(f);
  return (u + 0x7FFFu + ((u >> 16) & 1u)) >> 16;
}
__device__ __forceinline__ float bflo(u32 u) {
  return __uint_as_float(u << 16);
}
__device__ __forceinline__ float bfhi(u32 u) {
  return __uint_as_float(u & 0xFFFF0000u);
}

// ---------------- build pipeline ----------------

__global__ __launch_bounds__(256) void hist_tiles(
    const int* __restrict__ rows, int nnz, int ewg, int T,
    int* __restrict__ hist_g) {
  __shared__ int h[4][256];
  int w = blockIdx.x, tid = threadIdx.x;
  int wv = tid >> 6;
  for (int i = tid; i < 1024; i += 256) ((int*)h)[i] = 0;
  __syncthreads();
  int base = w * ewg;
  int end = min(base + ewg, nnz);
  for (int e = base + tid; e < end; e += 256)
    atomicAdd(&h[wv][rows[e] >> TSHIFT], 1);
  __syncthreads();
  if (tid < T)
    hist_g[tid * PW + w] = h[0][tid] + h[1][tid] + h[2][tid] + h[3][tid];
}

__global__ __launch_bounds__(512) void scan_chunks512(
    const int* __restrict__ in, int n, int* __restrict__ scanned,
    int* __restrict__ partials) {
  __shared__ int s[512];
  int t = threadIdx.x;
  int g = blockIdx.x * 512 + t;
  s[t] = (g < n) ? in[g] : 0;
  __syncthreads();
  for (int off = 1; off < 512; off <<= 1) {
    int v = (t >= off) ? s[t - off] : 0;
    __syncthreads();
    s[t] += v;
    __syncthreads();
  }
  if (g < n) scanned[g] = s[t];
  if (t == 511) partials[blockIdx.x] = s[511];
}

__global__ __launch_bounds__(1024) void scan_partials(
    int* __restrict__ partials, int nblk) {
  __shared__ int s[1024];
  int t = threadIdx.x;
  s[t] = (t < nblk) ? partials[t] : 0;
  __syncthreads();
  for (int off = 1; off < 1024; off <<= 1) {
    int v = (t >= off) ? s[t - off] : 0;
    __syncthreads();
    s[t] += v;
    __syncthreads();
  }
  if (t < nblk) partials[t] = (t == 0) ? 0 : s[t - 1];
}

__global__ __launch_bounds__(512) void finalize_offs(
    const int* __restrict__ scanned, const int* __restrict__ partials,
    const int* __restrict__ src, int n, int* __restrict__ offs) {
  int g = blockIdx.x * 512 + threadIdx.x;
  if (g < n) offs[g] = scanned[g] + partials[blockIdx.x] - src[g];
}

__global__ __launch_bounds__(256) void partition_edges(
    const int* __restrict__ rows, const int* __restrict__ cols, int nnz,
    int ewg, int T, const int* __restrict__ hist_g,
    const int* __restrict__ offs, u32* __restrict__ bucket) {
  __shared__ int cnt[256], lstart[256], gbase[256], cur[256], sc[256];
  __shared__ u32 stage[STAGE_CAP];
  __shared__ int dstA[STAGE_CAP];
  int w = blockIdx.x, tid = threadIdx.x;
  int c = 0, gb = 0;
  if (tid < T) {
    c = hist_g[tid * PW + w];
    gb = offs[tid * PW + w];
  }
  cnt[tid] = c;
  gbase[tid] = gb;
  cur[tid] = 0;
  sc[tid] = c;
  __syncthreads();
  for (int off = 1; off < 256; off <<= 1) {
    int v = (tid >= off) ? sc[tid - off] : 0;
    __syncthreads();
    sc[tid] += v;
    __syncthreads();
  }
  lstart[tid] = sc[tid] - c;
  __syncthreads();
  int base = w * ewg;
  int end = min(base + ewg, nnz);
  for (int e = base + tid; e < end; e += 256) {
    int r = rows[e];
    int cc = cols[e];
    int t = r >> TSHIFT;
    int slot = atomicAdd(&cur[t], 1);
    int idx = lstart[t] + slot;
    stage[idx] = ((u32)(r & TMASK) << 18) | (u32)cc;
    dstA[idx] = gbase[t] + slot;
  }
  __syncthreads();
  int total = end - base;
  for (int i = tid; i < total; i += 256) bucket[dstA[i]] = stage[i];
}

__global__ __launch_bounds__(1024) void build_csr_tile(
    const u32* __restrict__ bucket, const int* __restrict__ offs, int T,
    int N, int nnz, int* __restrict__ row_ptr, u32* __restrict__ csr) {
  __shared__ int hist[1024], sc[1024], cur[1024];
  int t = blockIdx.x;
  int tid = threadIdx.x;
  int tstart = offs[t * PW];
  int tend = (t + 1 < T) ? offs[(t + 1) * PW] : nnz;
  hist[tid] = 0;
  __syncthreads();
  for (int e = tstart + tid; e < tend; e += 1024)
    atomicAdd(&hist[bucket[e] >> 18], 1);
  __syncthreads();
  sc[tid] = hist[tid];
  __syncthreads();
  for (int off = 1; off < 1024; off <<= 1) {
    int v = (tid >= off) ? sc[tid - off] : 0;
    __syncthreads();
    sc[tid] += v;
    __syncthreads();
  }
  int r = (t << TSHIFT) + tid;
  if (r < N) row_ptr[r + 1] = tstart + sc[tid];
  if (t == 0 && tid == 0) row_ptr[0] = 0;
  cur[tid] = tstart + sc[tid] - hist[tid];
  __syncthreads();
  for (int e = tstart + tid; e < tend; e += 1024) {
    u32 ent = bucket[e];
    int p = atomicAdd(&cur[ent >> 18], 1);
    csr[p] = ent & 0x3FFFFu;
  }
}

// ---------------- y0 = D^-1/2 * concat(ue,ie), bf16; sentinel row N = 0 ----

__global__ __launch_bounds__(256) void make_y0(
    const float4* __restrict__ ue, const float4* __restrict__ ie, int U,
    int N, const int* __restrict__ row_ptr, uint4* __restrict__ y0b) {
  int i = blockIdx.x * 256 + threadIdx.x;
  int n8 = (N + 1) * 8;
  if (i >= n8) return;
  int row = i >> 3, q = i & 7;
  if (row == N) {
    y0b[i] = make_uint4(0, 0, 0, 0);
    return;
  }
  int deg = row_ptr[row + 1] - row_ptr[row];
  float invs = rsqrtf((float)max(deg, 1));
  const float4* src = (row < U) ? (ue + (size_t)row * 16 + q * 2)
                                : (ie + (size_t)(row - U) * 16 + q * 2);
  float4 a = src[0], b = src[1];
  uint4 o;
  o.x = f2bf(a.x * invs) | (f2bf(a.y * invs) << 16);
  o.y = f2bf(a.z * invs) | (f2bf(a.w * invs) << 16);
  o.z = f2bf(b.x * invs) | (f2bf(b.y * invs) << 16);
  o.w = f2bf(b.z * invs) | (f2bf(b.w * invs) << 16);
  y0b[i] = o;
}

// ---------------- SpMM: one row per 8-lane group, 8 rows/wave ----------------
// y_out[r] = (Σ_c y_in[c]) / max(deg_r, 1). No cross-lane reduce needed.

#define ACC8(G)                                                              \
  s0 += bflo(G.x); s1 += bfhi(G.x);                                          \
  s2 += bflo(G.y); s3 += bfhi(G.y);                                          \
  s4 += bflo(G.z); s5 += bfhi(G.z);                                          \
  s6 += bflo(G.w); s7 += bfhi(G.w);

__global__ __launch_bounds__(256) void spmm_sum(
    const int* __restrict__ row_ptr, const u32* __restrict__ csr,
    const u16* __restrict__ yin, u16* __restrict__ yout, int n) {
  if (blockIdx.x == 0 && threadIdx.x < 8)  // zero sentinel row of output
    ((uint4*)(yout + (size_t)n * DIM))[threadIdx.x] = make_uint4(0, 0, 0, 0);
  int row = (blockIdx.x * 256 + threadIdx.x) >> 3;
  int q8 = threadIdx.x & 7;
  if (row >= n) return;
  int start = row_ptr[row];
  int end = row_ptr[row + 1];
  float s0 = 0.f, s1 = 0.f, s2 = 0.f, s3 = 0.f;
  float s4 = 0.f, s5 = 0.f, s6 = 0.f, s7 = 0.f;
  int k = start;
  for (; k + 4 <= end; k += 4) {
    u32 c0 = csr[k];
    u32 c1 = csr[k + 1];
    u32 c2 = csr[k + 2];
    u32 c3 = csr[k + 3];
    uint4 g0 = ((const uint4*)(yin + (size_t)c0 * DIM))[q8];
    uint4 g1 = ((const uint4*)(yin + (size_t)c1 * DIM))[q8];
    uint4 g2 = ((const uint4*)(yin + (size_t)c2 * DIM))[q8];
    uint4 g3 = ((const uint4*)(yin + (size_t)c3 * DIM))[q8];
    ACC8(g0) ACC8(g1) ACC8(g2) ACC8(g3)
  }
  for (; k < end; ++k) {
    u32 c0 = csr[k];
    uint4 g0 = ((const uint4*)(yin + (size_t)c0 * DIM))[q8];
    ACC8(g0)
  }
  float inv = 1.0f / (float)max(end - start, 1);
  uint4 o;
  o.x = f2bf(s0 * inv) | (f2bf(s1 * inv) << 16);
  o.y = f2bf(s2 * inv) | (f2bf(s3 * inv) << 16);
  o.z = f2bf(s4 * inv) | (f2bf(s5 * inv) << 16);
  o.w = f2bf(s6 * inv) | (f2bf(s7 * inv) << 16);
  ((uint4*)(yout + (size_t)row * DIM))[q8] = o;
}

// ---------------- fused layer-3 + scorer (unchanged, uses sentinel) -------

__device__ __forceinline__ void gather8(
    const int* __restrict__ row_ptr, const u32* __restrict__ csr,
    const u16* __restrict__ y, int row, int s, int q8, int n, float* o) {
  int start = row_ptr[row];
  int end = row_ptr[row + 1];
  float s0 = 0.f, s1 = 0.f, s2 = 0.f, s3 = 0.f;
  float s4 = 0.f, s5 = 0.f, s6 = 0.f, s7 = 0.f;
  for (int k = start + s; k < end; k += 16) {
    int k2 = k + 8;
    bool ok2 = k2 < end;
    u32 c0 = csr[k];
    u32 c1 = ok2 ? csr[k2] : (u32)n;
    uint4 g0 = ((const uint4*)(y + (size_t)c0 * DIM))[q8];
    uint4 g1 = ((const uint4*)(y + (size_t)c1 * DIM))[q8];
    ACC8(g0) ACC8(g1)
  }
  for (int m = 8; m <= 32; m <<= 1) {
    s0 += __shfl_xor(s0, m, 64); s1 += __shfl_xor(s1, m, 64);
    s2 += __shfl_xor(s2, m, 64); s3 += __shfl_xor(s3, m, 64);
    s4 += __shfl_xor(s4, m, 64); s5 += __shfl_xor(s5, m, 64);
    s6 += __shfl_xor(s6, m, 64); s7 += __shfl_xor(s7, m, 64);
  }
  o[0] = s0; o[1] = s1; o[2] = s2; o[3] = s3;
  o[4] = s4; o[5] = s5; o[6] = s6; o[7] = s7;
}

__global__ __launch_bounds__(256) void spmm3_score(
    const int* __restrict__ row_ptr, const u32* __restrict__ csr,
    const float* __restrict__ ue, const float* __restrict__ ie,
    const u16* __restrict__ y1b, const u16* __restrict__ y2b,
    const int* __restrict__ user_ids, const int* __restrict__ item_ids,
    int U, int N, int batch, float* __restrict__ out) {
  int w = (blockIdx.x * 256 + threadIdx.x) >> 6;
  int lane = threadIdx.x & 63;
  if (w >= batch) return;
  int s = lane >> 3;
  int q8 = lane & 7;
  int u = user_ids[w];
  int iti = item_ids[w];
  int it = iti + U;
  float gu[8], gi[8];
  gather8(row_ptr, csr, y2b, u, s, q8, N, gu);
  gather8(row_ptr, csr, y2b, it, s, q8, N, gi);
  int du = row_ptr[u + 1] - row_ptr[u];
  int di = row_ptr[it + 1] - row_ptr[it];
  float su = sqrtf((float)max(du, 1)), ru = 1.0f / su;
  float si = sqrtf((float)max(di, 1)), ri = 1.0f / si;
  const float4* pu = (const float4*)(ue + (size_t)u * DIM) + q8 * 2;
  const float4* pi = (const float4*)(ie + (size_t)iti * DIM) + q8 * 2;
  float4 a0a = pu[0], a0b = pu[1];
  float4 b0a = pi[0], b0b = pi[1];
  uint4 y1u = ((const uint4*)(y1b + (size_t)u * DIM))[q8];
  uint4 y2u = ((const uint4*)(y2b + (size_t)u * DIM))[q8];
  uint4 y1i = ((const uint4*)(y1b + (size_t)it * DIM))[q8];
  uint4 y2i = ((const uint4*)(y2b + (size_t)it * DIM))[q8];
  float a[8], b[8];
  a[0] = a0a.x + su * (bflo(y1u.x) + bflo(y2u.x)) + ru * gu[0];
  a[1] = a0a.y + su * (bfhi(y1u.x) + bfhi(y2u.x)) + ru * gu[1];
  a[2] = a0a.z + su * (bflo(y1u.y) + bflo(y2u.y)) + ru * gu[2];
  a[3] = a0a.w + su * (bfhi(y1u.y) + bfhi(y2u.y)) + ru * gu[3];
  a[4] = a0b.x + su * (bflo(y1u.z) + bflo(y2u.z)) + ru * gu[4];
  a[5] = a0b.y + su * (bfhi(y1u.z) + bfhi(y2u.z)) + ru * gu[5];
  a[6] = a0b.z + su * (bflo(y1u.w) + bflo(y2u.w)) + ru * gu[6];
  a[7] = a0b.w + su * (bfhi(y1u.w) + bfhi(y2u.w)) + ru * gu[7];
  b[0] = b0a.x + si * (bflo(y1i.x) + bflo(y2i.x)) + ri * gi[0];
  b[1] = b0a.y + si * (bfhi(y1i.x) + bfhi(y2i.x)) + ri * gi[1];
  b[2] = b0a.z + si * (bflo(y1i.y) + bflo(y2i.y)) + ri * gi[2];
  b[3] = b0a.w + si * (bfhi(y1i.y) + bfhi(y2i.y)) + ri * gi[3];
  b[4] = b0b.x + si * (bflo(y1i.z) + bflo(y2i.z)) + ri * gi[4];
  b[5] = b0b.y + si * (bfhi(y1i.z) + bfhi(y2i.z)) + ri * gi[5];
  b[6] = b0b.z + si * (bflo(y1i.w) + bflo(y2i.w)) + ri * gi[6];
  b[7] = b0b.w + si * (bfhi(y1i.w) + bfhi(y2i.w)) + ri * gi[7];
  float p = 0.f;
  for (int j = 0; j < 8; ++j) p += a[j] * b[j];
  p += __shfl_xor(p, 1, 64);
  p += __shfl_xor(p, 2, 64);
  p += __shfl_xor(p, 4, 64);
  if (lane == 0) out[w] = p * (1.0f / 16.0f);
}

extern "C" void kernel_launch(void* const* d_in, const int* in_sizes, int n_in,
                              void* d_out, int out_size, void* d_ws, size_t ws_size,
                              hipStream_t stream) {
  const float* user_emb = (const float*)d_in[0];
  const float* item_emb = (const float*)d_in[1];
  const int* adj_rows = (const int*)d_in[3];
  const int* adj_cols = (const int*)d_in[4];
  const int* user_ids = (const int*)d_in[5];
  const int* item_ids = (const int*)d_in[6];
  float* scores = (float*)d_out;

  const int U = in_sizes[0] / DIM;  // 100000
  const int I = in_sizes[1] / DIM;  // 50000
  const int N = U + I;              // 150000
  const int nnz = in_sizes[2];      // 3200000
  const int B = in_sizes[5];        // 4096

  const int T = (N + TMASK) >> TSHIFT;  // 147
  const int TW = T * PW;
  const int ewg = (nnz + PW - 1) / PW;  // 3125

  char* p = (char*)d_ws;
  auto carve = [&](size_t bytes) {
    void* r = (void*)p;
    p += (bytes + 255) & ~(size_t)255;
    return r;
  };
  u16* y0b = (u16*)carve((size_t)(N + 1) * DIM * 2);
  u16* y1b = (u16*)carve((size_t)(N + 1) * DIM * 2);
  u16* y2b = (u16*)carve((size_t)(N + 1) * DIM * 2);
  int* hist_g = (int*)carve((size_t)TW * 4);
  int* scanned = (int*)carve((size_t)TW * 4);
  int* partials = (int*)carve((size_t)1024 * 4);
  int* row_ptr = (int*)carve((size_t)(N + 1) * 4);
  int* offs = (int*)carve((size_t)TW * 4);
  u32* bucket = (u32*)carve((size_t)nnz * 4);
  u32* csr = (u32*)carve((size_t)nnz * 4);

  // build pipeline
  hist_tiles<<<PW, 256, 0, stream>>>(adj_rows, nnz, ewg, T, hist_g);
  const int nchunk = (TW + 511) / 512;
  scan_chunks512<<<nchunk, 512, 0, stream>>>(hist_g, TW, scanned, partials);
  scan_partials<<<1, 1024, 0, stream>>>(partials, nchunk);
  finalize_offs<<<nchunk, 512, 0, stream>>>(scanned, partials, hist_g, TW,
                                            offs);
  partition_edges<<<PW, 256, 0, stream>>>(adj_rows, adj_cols, nnz, ewg, T,
                                          hist_g, offs, bucket);
  build_csr_tile<<<T, 1024, 0, stream>>>(bucket, offs, T, N, nnz, row_ptr,
                                         csr);

  // y0 (needs row_ptr for deg)
  const int n8 = (N + 1) * 8;
  make_y0<<<(n8 + 255) / 256, 256, 0, stream>>>(
      (const float4*)user_emb, (const float4*)item_emb, U, N, row_ptr,
      (uint4*)y0b);

  const int sblocks = (N * 8 + 255) / 256;  // 8 lanes per row
  spmm_sum<<<sblocks, 256, 0, stream>>>(row_ptr, csr, y0b, y1b, N);
  spmm_sum<<<sblocks, 256, 0, stream>>>(row_ptr, csr, y1b, y2b, N);

  spmm3_score<<<(B + 3) / 4, 256, 0, stream>>>(row_ptr, csr, user_emb,
                                               item_emb, y1b, y2b, user_ids,
                                               item_ids, U, N, B, scores);
}